// Round 3
// baseline (312.435 us; speedup 1.0000x reference)
//
#include <hip/hip_runtime.h>
#include <stdint.h>

// Problem constants (fixed by the reference)
#define NB       32
#define NC       128
#define NHW      1024            // H*W
#define NT       32768           // tokens
#define NE       16
#define NHID     512

typedef __attribute__((ext_vector_type(8))) short short8v;   // 8 x bf16 (4 VGPRs)
typedef __attribute__((ext_vector_type(4))) float f32x4;

__device__ __forceinline__ unsigned short f2bf(float f) {
    uint32_t u = __float_as_uint(f);
    uint32_t r = u + 0x7fffu + ((u >> 16) & 1u);   // RNE (finite values)
    return (unsigned short)(r >> 16);
}

// ---------------- Threefry-2x32, 20 rounds (JAX) ----------------
__device__ __forceinline__ uint32_t rotl32(uint32_t x, uint32_t d) {
    return (x << d) | (x >> (32u - d));
}

__device__ __forceinline__ void threefry2x32_20(uint32_t k0, uint32_t k1,
                                                uint32_t& x0, uint32_t& x1) {
    const uint32_t ks0 = k0, ks1 = k1, ks2 = k0 ^ k1 ^ 0x1BD11BDAu;
    x0 += ks0; x1 += ks1;
#define TFR(r) { x0 += x1; x1 = rotl32(x1, r); x1 ^= x0; }
    TFR(13u) TFR(15u) TFR(26u) TFR(6u)
    x0 += ks1; x1 += ks2 + 1u;
    TFR(17u) TFR(29u) TFR(16u) TFR(24u)
    x0 += ks2; x1 += ks0 + 2u;
    TFR(13u) TFR(15u) TFR(26u) TFR(6u)
    x0 += ks0; x1 += ks1 + 3u;
    TFR(17u) TFR(29u) TFR(16u) TFR(24u)
    x0 += ks1; x1 += ks2 + 4u;
    TFR(13u) TFR(15u) TFR(26u) TFR(6u)
    x0 += ks2; x1 += ks0 + 5u;
#undef TFR
}

__device__ __forceinline__ float erfinv_xla_f32(float x) {
    float w = -log1pf(-x * x);
    float p;
    if (w < 5.0f) {
        w = w - 2.5f;
        p = 2.81022636e-08f;
        p = fmaf(p, w, 3.43273939e-07f);
        p = fmaf(p, w, -3.5233877e-06f);
        p = fmaf(p, w, -4.39150654e-06f);
        p = fmaf(p, w, 0.00021858087f);
        p = fmaf(p, w, -0.00125372503f);
        p = fmaf(p, w, -0.00417768164f);
        p = fmaf(p, w, 0.246640727f);
        p = fmaf(p, w, 1.50140941f);
    } else {
        w = sqrtf(w) - 3.0f;
        p = -0.000200214257f;
        p = fmaf(p, w, 0.000100950558f);
        p = fmaf(p, w, 0.00134934322f);
        p = fmaf(p, w, -0.00367342844f);
        p = fmaf(p, w, 0.00573950773f);
        p = fmaf(p, w, -0.0076224613f);
        p = fmaf(p, w, 0.00943887047f);
        p = fmaf(p, w, 1.00167406f);
        p = fmaf(p, w, 2.83297682f);
    }
    return p * x;
}

__device__ __forceinline__ float jax_noise_elem(uint32_t i) {
    uint32_t x0 = 0u, x1 = i;
    threefry2x32_20(0u, 42u, x0, x1);
    uint32_t bits = x0 ^ x1;
    float f = __uint_as_float(0x3f800000u | (bits >> 9)) - 1.0f;
    const float lo = -0.99999994f;
    float u = f * 2.0f + lo;
    u = fmaxf(lo, u);
    return 1.41421354f * erfinv_xla_f32(u);
}

// ---------------- Kernel A: gating + noise + top-2 (token-per-thread) ---------
// Weights are wave-uniform -> s_load (SGPR operands); x reads coalesced (lane=hw).
__global__ __launch_bounds__(64) void moe_gate_kernel(
    const float* __restrict__ x,
    const float* __restrict__ gate_w, const float* __restrict__ gate_b,
    const float* __restrict__ noise_w, const float* __restrict__ noise_b,
    float* __restrict__ gates_out,        // [T,16] region of d_out
    int*   __restrict__ top_idx,          // [T,2]
    float* __restrict__ top_prob,         // [T,2]
    int*   __restrict__ rank,             // [T,2]
    int*   __restrict__ cnt,              // [16]
    int do_new)
{
    const int t  = blockIdx.x * 64 + (int)threadIdx.x;   // token
    const int b  = t >> 10, hw = t & 1023;

    float accg[16], accn[16];
    #pragma unroll
    for (int e = 0; e < 16; ++e) { accg[e] = gate_b[e]; accn[e] = noise_b[e]; }

    const float* xp = x + (size_t)b * (NC * NHW) + hw;
    #pragma unroll 8
    for (int c = 0; c < 128; ++c) {
        float xv = xp[(size_t)c << 10];          // coalesced across lanes
        const float* gwc = gate_w  + c * 16;     // uniform -> scalar loads
        const float* nwc = noise_w + c * 16;
        #pragma unroll
        for (int e = 0; e < 16; ++e) {
            accg[e] = fmaf(xv, gwc[e], accg[e]);
            accn[e] = fmaf(xv, nwc[e], accn[e]);
        }
    }

    // noisy logits in place: accg[e] = gate + nz * softplus(noise)
    #pragma unroll
    for (int e = 0; e < 16; ++e) {
        float an = accn[e];
        float sd = fmaxf(an, 0.f) + log1pf(expf(-fabsf(an)));
        float nz = jax_noise_elem((uint32_t)t * 16u + (uint32_t)e);
        accg[e] = fmaf(nz, sd, accg[e]);
    }

    // top-2, lowest-index tie-break (matches lax.top_k)
    float v1 = -INFINITY; int e1 = 0;
    #pragma unroll
    for (int e = 0; e < 16; ++e) {
        float v = accg[e];
        if (v > v1) { v1 = v; e1 = e; }
    }
    float v2 = -INFINITY; int e2 = 0;
    #pragma unroll
    for (int e = 0; e < 16; ++e) {
        float v = accg[e];
        if (e != e1 && v > v2) { v2 = v; e2 = e; }
    }
    float q  = expf(v2 - v1);
    float s  = 1.0f + q;
    float p1 = 1.0f / s;
    float p2 = q / s;

    float g[16];
    #pragma unroll
    for (int e = 0; e < 16; ++e)
        g[e] = (e == e1) ? p1 : ((e == e2) ? p2 : 0.f);
    f32x4* gp = (f32x4*)(gates_out + (size_t)t * 16);
    gp[0] = (f32x4){g[0], g[1], g[2], g[3]};
    gp[1] = (f32x4){g[4], g[5], g[6], g[7]};
    gp[2] = (f32x4){g[8], g[9], g[10], g[11]};
    gp[3] = (f32x4){g[12], g[13], g[14], g[15]};

    top_idx[t * 2 + 0] = e1;  top_idx[t * 2 + 1] = e2;
    top_prob[t * 2 + 0] = p1; top_prob[t * 2 + 1] = p2;
    if (do_new) {
        rank[t * 2 + 0] = atomicAdd(&cnt[e1], 1);
        rank[t * 2 + 1] = atomicAdd(&cnt[e2], 1);
    }
}

// ---------------- transpose + f32->bf16 convert: dst[e][c][r] = src[e][r][c] --
__global__ __launch_bounds__(256) void transpose_convert_kernel(
    const float* __restrict__ src, unsigned short* __restrict__ dst, int R, int C)
{
    __shared__ float ts[64][65];
    const int nr = R >> 6, ncc = C >> 6;
    const int blk = blockIdx.x;
    const int e = blk / (nr * ncc);
    const int rem = blk % (nr * ncc);
    const int rt = rem / ncc, ct = rem % ncc;
    const float* S = src + (size_t)e * R * C + (size_t)(rt * 64) * C + ct * 64;
    unsigned short* D = dst + (size_t)e * R * C + (size_t)(ct * 64) * R + rt * 64;
    const int tid = threadIdx.x;
    #pragma unroll
    for (int i = 0; i < 16; ++i) {
        int lin = i * 256 + tid;
        int r = lin >> 6, c = lin & 63;
        ts[r][c] = S[(size_t)r * C + c];
    }
    __syncthreads();
    #pragma unroll
    for (int i = 0; i < 16; ++i) {
        int lin = i * 256 + tid;
        int c = lin >> 6, r = lin & 63;
        D[(size_t)c * R + r] = f2bf(ts[r][c]);
    }
}

// ---------------- scan: padded offsets, block->(e,chunk) table, pad fill ------
__global__ __launch_bounds__(256) void scan_kernel(
    const int* __restrict__ cnt,
    int* __restrict__ poff, int* __restrict__ blk2e,
    int* __restrict__ blk2chunk, int* __restrict__ total_chunks,
    int* __restrict__ pair_tok)
{
    __shared__ int snch[16];
    __shared__ int scum[17];
    __shared__ int spoff[16];
    const int tid = threadIdx.x;
    if (tid < 16) snch[tid] = (cnt[tid] + 127) >> 7;
    __syncthreads();
    if (tid == 0) {
        int cc = 0, off = 0;
        for (int e = 0; e < 16; ++e) {
            scum[e] = cc; spoff[e] = off;
            cc += snch[e]; off += snch[e] << 7;
        }
        scum[16] = cc;
        *total_chunks = cc;
    }
    __syncthreads();
    const int tot = scum[16];
    for (int idx = tid; idx < tot; idx += 256) {
        int e = 0;
        #pragma unroll
        for (int k = 0; k < 15; ++k)
            if (idx >= scum[k + 1]) e = k + 1;
        blk2e[idx] = e;
        blk2chunk[idx] = idx - scum[e];
    }
    if (tid < 16) poff[tid] = spoff[tid];
    for (int e = 0; e < 16; ++e) {
        int start = spoff[e] + cnt[e];
        int end   = spoff[e] + (snch[e] << 7);
        for (int i = start + tid; i < end; i += 256)
            pair_tok[i] = -1;
    }
}

// ---------------- scatter pairs into expert bins ------------------------------
__global__ __launch_bounds__(256) void scatter_kernel(
    const int* __restrict__ top_idx, const int* __restrict__ rank,
    const int* __restrict__ poff, int* __restrict__ pair_tok,
    int* __restrict__ slot_of)
{
    int i = blockIdx.x * 256 + threadIdx.x;   // 0..65535
    int t = i >> 1;
    int e = top_idx[i];
    int slot = poff[e] + rank[i];
    pair_tok[slot] = t;
    slot_of[i] = slot;
}

// ---------------- grouped MFMA MLP: 1 block = (expert, 128 pairs) -------------
__global__ __launch_bounds__(512, 1) void moe_mfma_kernel(
    const unsigned short* __restrict__ xtb,
    const int* __restrict__ pair_tok, const int* __restrict__ blk2e,
    const int* __restrict__ blk2chunk, const int* __restrict__ poff,
    const int* __restrict__ total_chunks,
    const unsigned short* __restrict__ w1bt,   // [E][HID][D] bf16
    const float* __restrict__ b1,
    const unsigned short* __restrict__ w2bt,   // [E][D][HID] bf16
    const float* __restrict__ b2,
    float* __restrict__ pair_y)                // [Ppad][128] f32
{
    __shared__ short Xs[128 * 136];
    __shared__ short Hs[128 * 136];
    __shared__ short W1t[128 * 136];   // rows: h_local, cols: d
    __shared__ short W2t[128 * 136];   // rows: d, cols: h_local
    __shared__ int   ptoks[128];

    const int blk = blockIdx.x;
    if (blk >= *total_chunks) return;
    const int e  = blk2e[blk];
    const int p0 = poff[e] + (blk2chunk[blk] << 7);
    const int tid  = threadIdx.x;
    const int lane = tid & 63;
    const int wid  = tid >> 6;       // 0..7
    const int wm   = wid >> 1;       // 0..3 -> m0 = wm*32
    const int wn   = wid & 1;        // 0..1 -> n0 = wn*64
    const int l16  = lane & 15;
    const int lg   = lane >> 4;      // 0..3

    if (tid < 128) ptoks[tid] = pair_tok[p0 + tid];
    __syncthreads();

    #pragma unroll
    for (int i = 0; i < 4; ++i) {
        int lin = i * 512 + tid;              // 0..2047
        int row = lin >> 4, kc = lin & 15;
        int tok = ptoks[row];
        short8v v = {};
        if (tok >= 0)
            v = *(const short8v*)(xtb + (size_t)tok * 128 + kc * 8);
        *(short8v*)(Xs + row * 136 + kc * 8) = v;
    }

    f32x4 yacc[2][4];
    #pragma unroll
    for (int mi = 0; mi < 2; ++mi)
        #pragma unroll
        for (int ni = 0; ni < 4; ++ni)
            yacc[mi][ni] = (f32x4){0.f, 0.f, 0.f, 0.f};

    const size_t w1base = (size_t)e * 512 * 128;
    const size_t w2base = (size_t)e * 128 * 512;

    for (int c = 0; c < 4; ++c) {
        const int hc = c << 7;
        #pragma unroll
        for (int i = 0; i < 4; ++i) {
            int lin = i * 512 + tid;
            int row = lin >> 4, kc = lin & 15;
            short8v v = *(const short8v*)(w1bt + w1base + (size_t)(hc + row) * 128 + kc * 8);
            *(short8v*)(W1t + row * 136 + kc * 8) = v;
        }
        #pragma unroll
        for (int i = 0; i < 4; ++i) {
            int lin = i * 512 + tid;
            int row = lin >> 4, kc = lin & 15;
            short8v v = *(const short8v*)(w2bt + w2base + (size_t)row * 512 + hc + kc * 8);
            *(short8v*)(W2t + row * 136 + kc * 8) = v;
        }
        __syncthreads();

        // ---- layer 1: H = relu(X @ W1 + b1), this 128-wide hid chunk ----
        f32x4 hacc[2][4];
        #pragma unroll
        for (int mi = 0; mi < 2; ++mi)
            #pragma unroll
            for (int ni = 0; ni < 4; ++ni)
                hacc[mi][ni] = (f32x4){0.f, 0.f, 0.f, 0.f};

        #pragma unroll
        for (int kk = 0; kk < 4; ++kk) {
            short8v a0 = *(const short8v*)(Xs + (wm * 32 +      l16) * 136 + kk * 32 + lg * 8);
            short8v a1 = *(const short8v*)(Xs + (wm * 32 + 16 + l16) * 136 + kk * 32 + lg * 8);
            #pragma unroll
            for (int ni = 0; ni < 4; ++ni) {
                short8v bfr = *(const short8v*)(W1t + (wn * 64 + ni * 16 + l16) * 136 + kk * 32 + lg * 8);
                hacc[0][ni] = __builtin_amdgcn_mfma_f32_16x16x32_bf16(a0, bfr, hacc[0][ni], 0, 0, 0);
                hacc[1][ni] = __builtin_amdgcn_mfma_f32_16x16x32_bf16(a1, bfr, hacc[1][ni], 0, 0, 0);
            }
        }
        #pragma unroll
        for (int ni = 0; ni < 4; ++ni) {
            float b1v = b1[e * 512 + hc + wn * 64 + ni * 16 + l16];
            #pragma unroll
            for (int mi = 0; mi < 2; ++mi) {
                #pragma unroll
                for (int r = 0; r < 4; ++r) {
                    float v = fmaxf(hacc[mi][ni][r] + b1v, 0.f);
                    Hs[(wm * 32 + mi * 16 + lg * 4 + r) * 136 + wn * 64 + ni * 16 + l16] =
                        (short)f2bf(v);
                }
            }
        }
        __syncthreads();

        // ---- layer 2: Y += H_chunk @ W2[hc:hc+128, :] ----
        #pragma unroll
        for (int kk = 0; kk < 4; ++kk) {
            short8v a0 = *(const short8v*)(Hs + (wm * 32 +      l16) * 136 + kk * 32 + lg * 8);
            short8v a1 = *(const short8v*)(Hs + (wm * 32 + 16 + l16) * 136 + kk * 32 + lg * 8);
            #pragma unroll
            for (int ni = 0; ni < 4; ++ni) {
                short8v bfr = *(const short8v*)(W2t + (wn * 64 + ni * 16 + l16) * 136 + kk * 32 + lg * 8);
                yacc[0][ni] = __builtin_amdgcn_mfma_f32_16x16x32_bf16(a0, bfr, yacc[0][ni], 0, 0, 0);
                yacc[1][ni] = __builtin_amdgcn_mfma_f32_16x16x32_bf16(a1, bfr, yacc[1][ni], 0, 0, 0);
            }
        }
        __syncthreads();
    }

    #pragma unroll
    for (int ni = 0; ni < 4; ++ni) {
        int d = wn * 64 + ni * 16 + l16;
        float b2v = b2[e * 128 + d];
        #pragma unroll
        for (int mi = 0; mi < 2; ++mi) {
            #pragma unroll
            for (int r = 0; r < 4; ++r) {
                int m = wm * 32 + mi * 16 + lg * 4 + r;
                pair_y[(size_t)(p0 + m) * 128 + d] = yacc[mi][ni][r] + b2v;
            }
        }
    }
}

// ---------------- combine: out[t] = p0*y0 + p1*y1 (NCHW store) ----------------
__global__ __launch_bounds__(256) void combine_kernel(
    const float* __restrict__ pair_y, const int* __restrict__ slot_of,
    const float* __restrict__ top_prob, float* __restrict__ out)
{
    __shared__ float ob[64][129];
    const int blk = blockIdx.x;               // 512
    const int b = blk >> 4;
    const int hw0 = (blk & 15) << 6;
    const int tid = threadIdx.x;
    #pragma unroll
    for (int i = 0; i < 32; ++i) {
        int lin = i * 256 + tid;
        int tl = lin >> 7, d = lin & 127;
        int t = b * 1024 + hw0 + tl;
        int s0 = slot_of[t * 2], s1 = slot_of[t * 2 + 1];
        float p0 = top_prob[t * 2], p1 = top_prob[t * 2 + 1];
        ob[tl][d] = p0 * pair_y[(size_t)s0 * 128 + d] + p1 * pair_y[(size_t)s1 * 128 + d];
    }
    __syncthreads();
    #pragma unroll
    for (int i = 0; i < 32; ++i) {
        int lin = i * 256 + tid;
        int d = lin >> 6, hwl = lin & 63;
        out[((size_t)b * 128 + d) * 1024 + hw0 + hwl] = ob[hwl][d];
    }
}

// ---------------- fallback per-token expert kernel ----------------------------
__global__ __launch_bounds__(256) void moe_expert_kernel(
    const float* __restrict__ x,
    const int* __restrict__ top_idx, const float* __restrict__ top_prob,
    const float* __restrict__ w1, const float* __restrict__ b1,
    const float* __restrict__ w2, const float* __restrict__ b2,
    float* __restrict__ out)
{
    __shared__ float xsB[128];
    __shared__ float hb[512];

    const int tid = threadIdx.x;
    const int t = blockIdx.x;
    const int b = t >> 10, hw = t & 1023;

    if (tid < 128)
        xsB[tid] = x[((size_t)b * 128 + tid) * NHW + hw];
    __syncthreads();

    float oacc = 0.f;
    #pragma unroll
    for (int k = 0; k < 2; ++k) {
        const int e = top_idx[t * 2 + k];
        const float pw = top_prob[t * 2 + k];
        const float* W1 = w1 + (size_t)e * (128 * 512);
        float a0 = 0.f, a1 = 0.f;
        for (int d = 0; d < 128; ++d) {
            float xv = xsB[d];
            a0 = fmaf(xv, W1[d * 512 + tid], a0);
            a1 = fmaf(xv, W1[d * 512 + tid + 256], a1);
        }
        hb[tid]       = fmaxf(a0 + b1[e * 512 + tid], 0.f);
        hb[tid + 256] = fmaxf(a1 + b1[e * 512 + tid + 256], 0.f);
        __syncthreads();
        if (tid < 128) {
            const float* W2 = w2 + (size_t)e * (512 * 128);
            float a = 0.f;
            for (int h = 0; h < 512; ++h)
                a = fmaf(hb[h], W2[h * 128 + tid], a);
            oacc = fmaf(pw, a + b2[e * 128 + tid], oacc);
        }
        __syncthreads();
    }
    if (tid < 128)
        out[((size_t)b * 128 + tid) * NHW + hw] = oacc;
}

// ---------------- host launch -------------------------------------------------
extern "C" void kernel_launch(void* const* d_in, const int* in_sizes, int n_in,
                              void* d_out, int out_size, void* d_ws, size_t ws_size,
                              hipStream_t stream) {
    const float* x       = (const float*)d_in[0];
    const float* gate_w  = (const float*)d_in[1];
    const float* gate_b  = (const float*)d_in[2];
    const float* noise_w = (const float*)d_in[3];
    const float* noise_b = (const float*)d_in[4];
    const float* w1      = (const float*)d_in[5];
    const float* b1      = (const float*)d_in[6];
    const float* w2      = (const float*)d_in[7];
    const float* b2      = (const float*)d_in[8];

    float* out   = (float*)d_out;                   // [32,128,32,32]
    float* gates = out + (size_t)NB * NC * NHW;     // [T,16]

    // workspace layout (byte offsets)
    const size_t OFF_CNT    = 0;          // 16 ints
    const size_t OFF_POFF   = 1024;       // 16 ints
    const size_t OFF_TOTAL  = 2048;       // 1 int
    const size_t OFF_B2E    = 4096;       // 544 ints
    const size_t OFF_B2C    = 8192;       // 544 ints
    const size_t OFF_TIDX   = 12288;      // T*2 ints
    const size_t OFF_RANK   = OFF_TIDX + (size_t)NT * 2 * 4;
    const size_t OFF_SLOT   = OFF_RANK + (size_t)NT * 2 * 4;
    const size_t OFF_PROB   = OFF_SLOT + (size_t)NT * 2 * 4;
    const size_t OFF_XTB    = OFF_PROB + (size_t)NT * 2 * 4;
    const size_t OFF_W1BT   = OFF_XTB + (size_t)NT * 128 * 2;
    const size_t OFF_W2BT   = OFF_W1BT + (size_t)NE * 512 * 128 * 2;
    const size_t OFF_PTOK   = OFF_W2BT + (size_t)NE * 128 * 512 * 2;
    const size_t NPAIR_PAD  = 67584;
    const size_t OFF_PAIRY  = OFF_PTOK + NPAIR_PAD * 4;
    const size_t NEED       = OFF_PAIRY + NPAIR_PAD * 128 * 4;

    char* ws = (char*)d_ws;
    int*   cnt      = (int*)(ws + OFF_CNT);
    int*   poff     = (int*)(ws + OFF_POFF);
    int*   total_ch = (int*)(ws + OFF_TOTAL);
    int*   blk2e    = (int*)(ws + OFF_B2E);
    int*   blk2c    = (int*)(ws + OFF_B2C);
    int*   top_idx  = (int*)(ws + OFF_TIDX);
    int*   rank     = (int*)(ws + OFF_RANK);
    int*   slot_of  = (int*)(ws + OFF_SLOT);
    float* top_prob = (float*)(ws + OFF_PROB);
    unsigned short* xtb  = (unsigned short*)(ws + OFF_XTB);
    unsigned short* w1bt = (unsigned short*)(ws + OFF_W1BT);
    unsigned short* w2bt = (unsigned short*)(ws + OFF_W2BT);
    int*   pair_tok = (int*)(ws + OFF_PTOK);
    float* pair_y   = (float*)(ws + OFF_PAIRY);

    const int use_new = (ws_size >= NEED) ? 1 : 0;

    if (use_new)
        hipMemsetAsync(cnt, 0, 16 * sizeof(int), stream);

    moe_gate_kernel<<<NT / 64, 64, 0, stream>>>(
        x, gate_w, gate_b, noise_w, noise_b,
        gates, top_idx, top_prob, rank, cnt, use_new);

    if (use_new) {
        // x[b][128][1024] -> xtb[b*1024+hw][128] bf16
        transpose_convert_kernel<<<NB * 2 * 16, 256, 0, stream>>>(x, xtb, 128, 1024);
        // w1[e][128][512] -> w1bt[e][512][128] ; w2[e][512][128] -> w2bt[e][128][512]
        transpose_convert_kernel<<<NE * 2 * 8, 256, 0, stream>>>(w1, w1bt, 128, 512);
        transpose_convert_kernel<<<NE * 8 * 2, 256, 0, stream>>>(w2, w2bt, 512, 128);
        scan_kernel<<<1, 256, 0, stream>>>(cnt, poff, blk2e, blk2c, total_ch, pair_tok);
        scatter_kernel<<<NT * 2 / 256, 256, 0, stream>>>(top_idx, rank, poff, pair_tok, slot_of);
        moe_mfma_kernel<<<528, 512, 0, stream>>>(
            xtb, pair_tok, blk2e, blk2c, poff, total_ch,
            w1bt, b1, w2bt, b2, pair_y);
        combine_kernel<<<512, 256, 0, stream>>>(pair_y, slot_of, top_prob, out);
    } else {
        moe_expert_kernel<<<NT, 256, 0, stream>>>(
            x, top_idx, top_prob, w1, b1, w2, b2, out);
    }
}

// Round 4
// 297.896 us; speedup vs baseline: 1.0488x; 1.0488x over previous
//
#include <hip/hip_runtime.h>
#include <stdint.h>

// Problem constants (fixed by the reference)
#define NB       32
#define NC       128
#define NHW      1024            // H*W
#define NT       32768           // tokens
#define NE       16
#define NHID     512

typedef __attribute__((ext_vector_type(8))) short short8v;   // 8 x bf16 (4 VGPRs)
typedef __attribute__((ext_vector_type(4))) float f32x4;

__device__ __forceinline__ unsigned short f2bf(float f) {
    uint32_t u = __float_as_uint(f);
    uint32_t r = u + 0x7fffu + ((u >> 16) & 1u);   // RNE (finite values)
    return (unsigned short)(r >> 16);
}

// ---------------- Threefry-2x32, 20 rounds (JAX) ----------------
__device__ __forceinline__ uint32_t rotl32(uint32_t x, uint32_t d) {
    return (x << d) | (x >> (32u - d));
}

__device__ __forceinline__ void threefry2x32_20(uint32_t k0, uint32_t k1,
                                                uint32_t& x0, uint32_t& x1) {
    const uint32_t ks0 = k0, ks1 = k1, ks2 = k0 ^ k1 ^ 0x1BD11BDAu;
    x0 += ks0; x1 += ks1;
#define TFR(r) { x0 += x1; x1 = rotl32(x1, r); x1 ^= x0; }
    TFR(13u) TFR(15u) TFR(26u) TFR(6u)
    x0 += ks1; x1 += ks2 + 1u;
    TFR(17u) TFR(29u) TFR(16u) TFR(24u)
    x0 += ks2; x1 += ks0 + 2u;
    TFR(13u) TFR(15u) TFR(26u) TFR(6u)
    x0 += ks0; x1 += ks1 + 3u;
    TFR(17u) TFR(29u) TFR(16u) TFR(24u)
    x0 += ks1; x1 += ks2 + 4u;
    TFR(13u) TFR(15u) TFR(26u) TFR(6u)
    x0 += ks2; x1 += ks0 + 5u;
#undef TFR
}

__device__ __forceinline__ float erfinv_xla_f32(float x) {
    float w = -log1pf(-x * x);
    float p;
    if (w < 5.0f) {
        w = w - 2.5f;
        p = 2.81022636e-08f;
        p = fmaf(p, w, 3.43273939e-07f);
        p = fmaf(p, w, -3.5233877e-06f);
        p = fmaf(p, w, -4.39150654e-06f);
        p = fmaf(p, w, 0.00021858087f);
        p = fmaf(p, w, -0.00125372503f);
        p = fmaf(p, w, -0.00417768164f);
        p = fmaf(p, w, 0.246640727f);
        p = fmaf(p, w, 1.50140941f);
    } else {
        w = sqrtf(w) - 3.0f;
        p = -0.000200214257f;
        p = fmaf(p, w, 0.000100950558f);
        p = fmaf(p, w, 0.00134934322f);
        p = fmaf(p, w, -0.00367342844f);
        p = fmaf(p, w, 0.00573950773f);
        p = fmaf(p, w, -0.0076224613f);
        p = fmaf(p, w, 0.00943887047f);
        p = fmaf(p, w, 1.00167406f);
        p = fmaf(p, w, 2.83297682f);
    }
    return p * x;
}

__device__ __forceinline__ float jax_noise_elem(uint32_t i) {
    uint32_t x0 = 0u, x1 = i;
    threefry2x32_20(0u, 42u, x0, x1);
    uint32_t bits = x0 ^ x1;
    float f = __uint_as_float(0x3f800000u | (bits >> 9)) - 1.0f;
    const float lo = -0.99999994f;
    float u = f * 2.0f + lo;
    u = fmaxf(lo, u);
    return 1.41421354f * erfinv_xla_f32(u);
}

// ---------------- Kernel A: gating + noise + top-2 ----------------------------
// 4 threads per token (c-split 32 each), 64 tokens/block, 256 threads.
// Weights in LDS at [ci][q][40] so the 4 q-groups' ds_read_b128 windows land on
// disjoint bank quartets (offsets 0,8,16,24 mod 32) -> conflict-free broadcast.
__global__ __launch_bounds__(256) void moe_gate_kernel(
    const float* __restrict__ x,
    const float* __restrict__ gate_w, const float* __restrict__ gate_b,
    const float* __restrict__ noise_w, const float* __restrict__ noise_b,
    float* __restrict__ gates_out,        // [T,16] region of d_out
    int*   __restrict__ top_idx,          // [T,2]
    float* __restrict__ top_prob,         // [T,2]
    int*   __restrict__ rank,             // [T,2]
    int*   __restrict__ cnt,              // [16]
    int do_new)
{
    __shared__ float lw[32 * 160];        // [ci=32][q=4][40]; e<16 gate, e>=16 noise

    const int tid = threadIdx.x;
    const int tl  = tid >> 2;                     // token within block (0..63)
    const int q   = tid & 3;                      // channel quarter
    const int t   = blockIdx.x * 64 + tl;         // global token
    const int b   = t >> 10, hw = t & 1023;

    // stage weights: lw[ci][q][e] = w[(q*32+ci)*16 + e]
    for (int idx = tid; idx < 4096; idx += 256) {
        int ci = idx >> 7;
        int r  = idx & 127;
        int qq = r >> 5, e = r & 31;
        int c  = qq * 32 + ci;
        float v = (e < 16) ? gate_w[c * 16 + e] : noise_w[c * 16 + (e - 16)];
        lw[ci * 160 + qq * 40 + e] = v;
    }
    __syncthreads();

    // partial dot over this thread's 32 channels
    float acc[32];
    #pragma unroll
    for (int e = 0; e < 32; ++e) acc[e] = 0.f;

    const float* xq = x + (size_t)b * (NC * NHW) + (size_t)(q * 32) * NHW + hw;
    const float* wq = lw + q * 40;
    #pragma unroll 4
    for (int ci = 0; ci < 32; ++ci) {
        float xv = xq[(size_t)ci << 10];
        const f32x4* wr = (const f32x4*)(wq + ci * 160);
        #pragma unroll
        for (int j = 0; j < 8; ++j) {
            f32x4 w4 = wr[j];
            #pragma unroll
            for (int k = 0; k < 4; ++k)
                acc[j * 4 + k] = fmaf(xv, w4[k], acc[j * 4 + k]);
        }
    }

    // butterfly reduce across the 4 q-lanes (q = lane bits 0-1)
    #pragma unroll
    for (int e = 0; e < 32; ++e) {
        acc[e] += __shfl_xor(acc[e], 1);
        acc[e] += __shfl_xor(acc[e], 2);
    }

    // this lane finishes experts e = q*4 .. q*4+3
    float lg[4];
    #pragma unroll
    for (int j = 0; j < 4; ++j) {
        int e = q * 4 + j;
        float g  = acc[e] + gate_b[e];
        float an = acc[16 + e] + noise_b[e];
        float sd = fmaxf(an, 0.f) + log1pf(expf(-fabsf(an)));
        float nz = jax_noise_elem((uint32_t)t * 16u + (uint32_t)e);
        lg[j] = fmaf(nz, sd, g);
    }

    // local top-2 (value desc, index asc — matches lax.top_k stability)
    float v1 = lg[0], v2 = -INFINITY;
    int   i1 = q * 4, i2 = 0x7fffffff;
    #pragma unroll
    for (int j = 1; j < 4; ++j) {
        float v = lg[j]; int e = q * 4 + j;
        if (v > v1) { v2 = v1; i2 = i1; v1 = v; i1 = e; }
        else if (v > v2) { v2 = v; i2 = e; }
    }
    // merge across q-lanes
    #pragma unroll
    for (int m = 1; m <= 2; m <<= 1) {
        float pv1 = __shfl_xor(v1, m), pv2 = __shfl_xor(v2, m);
        int   pi1 = __shfl_xor(i1, m), pi2 = __shfl_xor(i2, m);
        bool pBest = (pv1 > v1) || (pv1 == v1 && pi1 < i1);
        float c2v; int c2i;                 // the loser of the top-1 contest
        if (pBest) { c2v = v1;  c2i = i1;  v1 = pv1; i1 = pi1;
                     // second = better of (c2) vs (pv2)
                     if (!((c2v > pv2) || (c2v == pv2 && c2i < pi2))) { c2v = pv2; c2i = pi2; }
        } else     { c2v = pv1; c2i = pi1;
                     if (!((c2v > v2)  || (c2v == v2  && c2i < i2)))  { c2v = v2;  c2i = i2;  }
        }
        v2 = c2v; i2 = c2i;
    }

    float qq = expf(v2 - v1);
    float s  = 1.0f + qq;
    float p1 = 1.0f / s;
    float p2 = qq / s;

    // write this lane's 4 gate entries (wave stores are fully contiguous)
    f32x4 g4;
    #pragma unroll
    for (int j = 0; j < 4; ++j) {
        int e = q * 4 + j;
        g4[j] = (e == i1) ? p1 : ((e == i2) ? p2 : 0.f);
    }
    *(f32x4*)(gates_out + (size_t)t * 16 + q * 4) = g4;

    if (q == 0) {
        top_idx[t * 2 + 0] = i1;  top_idx[t * 2 + 1] = i2;
        top_prob[t * 2 + 0] = p1; top_prob[t * 2 + 1] = p2;
        if (do_new) {
            rank[t * 2 + 0] = atomicAdd(&cnt[i1], 1);
            rank[t * 2 + 1] = atomicAdd(&cnt[i2], 1);
        }
    }
}

// ---------------- transpose + f32->bf16 convert: dst[e][c][r] = src[e][r][c] --
__global__ __launch_bounds__(256) void transpose_convert_kernel(
    const float* __restrict__ src, unsigned short* __restrict__ dst, int R, int C)
{
    __shared__ float ts[64][65];
    const int nr = R >> 6, ncc = C >> 6;
    const int blk = blockIdx.x;
    const int e = blk / (nr * ncc);
    const int rem = blk % (nr * ncc);
    const int rt = rem / ncc, ct = rem % ncc;
    const float* S = src + (size_t)e * R * C + (size_t)(rt * 64) * C + ct * 64;
    unsigned short* D = dst + (size_t)e * R * C + (size_t)(ct * 64) * R + rt * 64;
    const int tid = threadIdx.x;
    #pragma unroll
    for (int i = 0; i < 16; ++i) {
        int lin = i * 256 + tid;
        int r = lin >> 6, c = lin & 63;
        ts[r][c] = S[(size_t)r * C + c];
    }
    __syncthreads();
    #pragma unroll
    for (int i = 0; i < 16; ++i) {
        int lin = i * 256 + tid;
        int c = lin >> 6, r = lin & 63;
        D[(size_t)c * R + r] = f2bf(ts[r][c]);
    }
}

// ---------------- scan: padded offsets, block->(e,chunk) table, pad fill ------
__global__ __launch_bounds__(256) void scan_kernel(
    const int* __restrict__ cnt,
    int* __restrict__ poff, int* __restrict__ blk2e,
    int* __restrict__ blk2chunk, int* __restrict__ total_chunks,
    int* __restrict__ pair_tok)
{
    __shared__ int snch[16];
    __shared__ int scum[17];
    __shared__ int spoff[16];
    const int tid = threadIdx.x;
    if (tid < 16) snch[tid] = (cnt[tid] + 127) >> 7;
    __syncthreads();
    if (tid == 0) {
        int cc = 0, off = 0;
        for (int e = 0; e < 16; ++e) {
            scum[e] = cc; spoff[e] = off;
            cc += snch[e]; off += snch[e] << 7;
        }
        scum[16] = cc;
        *total_chunks = cc;
    }
    __syncthreads();
    const int tot = scum[16];
    for (int idx = tid; idx < tot; idx += 256) {
        int e = 0;
        #pragma unroll
        for (int k = 0; k < 15; ++k)
            if (idx >= scum[k + 1]) e = k + 1;
        blk2e[idx] = e;
        blk2chunk[idx] = idx - scum[e];
    }
    if (tid < 16) poff[tid] = spoff[tid];
    for (int e = 0; e < 16; ++e) {
        int start = spoff[e] + cnt[e];
        int end   = spoff[e] + (snch[e] << 7);
        for (int i = start + tid; i < end; i += 256)
            pair_tok[i] = -1;
    }
}

// ---------------- scatter pairs into expert bins ------------------------------
__global__ __launch_bounds__(256) void scatter_kernel(
    const int* __restrict__ top_idx, const int* __restrict__ rank,
    const int* __restrict__ poff, int* __restrict__ pair_tok,
    int* __restrict__ slot_of)
{
    int i = blockIdx.x * 256 + threadIdx.x;   // 0..65535
    int t = i >> 1;
    int e = top_idx[i];
    int slot = poff[e] + rank[i];
    pair_tok[slot] = t;
    slot_of[i] = slot;
}

// ---------------- grouped MFMA MLP: 1 block = (expert, 128 pairs) -------------
__global__ __launch_bounds__(512, 1) void moe_mfma_kernel(
    const unsigned short* __restrict__ xtb,
    const int* __restrict__ pair_tok, const int* __restrict__ blk2e,
    const int* __restrict__ blk2chunk, const int* __restrict__ poff,
    const int* __restrict__ total_chunks,
    const unsigned short* __restrict__ w1bt,   // [E][HID][D] bf16
    const float* __restrict__ b1,
    const unsigned short* __restrict__ w2bt,   // [E][D][HID] bf16
    const float* __restrict__ b2,
    float* __restrict__ pair_y)                // [Ppad][128] f32
{
    __shared__ short Xs[128 * 136];
    __shared__ short Hs[128 * 136];
    __shared__ short W1t[128 * 136];   // rows: h_local, cols: d
    __shared__ short W2t[128 * 136];   // rows: d, cols: h_local
    __shared__ int   ptoks[128];

    const int blk = blockIdx.x;
    if (blk >= *total_chunks) return;
    const int e  = blk2e[blk];
    const int p0 = poff[e] + (blk2chunk[blk] << 7);
    const int tid  = threadIdx.x;
    const int lane = tid & 63;
    const int wid  = tid >> 6;       // 0..7
    const int wm   = wid >> 1;       // 0..3 -> m0 = wm*32
    const int wn   = wid & 1;        // 0..1 -> n0 = wn*64
    const int l16  = lane & 15;
    const int lg   = lane >> 4;      // 0..3

    if (tid < 128) ptoks[tid] = pair_tok[p0 + tid];
    __syncthreads();

    #pragma unroll
    for (int i = 0; i < 4; ++i) {
        int lin = i * 512 + tid;              // 0..2047
        int row = lin >> 4, kc = lin & 15;
        int tok = ptoks[row];
        short8v v = {};
        if (tok >= 0)
            v = *(const short8v*)(xtb + (size_t)tok * 128 + kc * 8);
        *(short8v*)(Xs + row * 136 + kc * 8) = v;
    }

    f32x4 yacc[2][4];
    #pragma unroll
    for (int mi = 0; mi < 2; ++mi)
        #pragma unroll
        for (int ni = 0; ni < 4; ++ni)
            yacc[mi][ni] = (f32x4){0.f, 0.f, 0.f, 0.f};

    const size_t w1base = (size_t)e * 512 * 128;
    const size_t w2base = (size_t)e * 128 * 512;

    for (int c = 0; c < 4; ++c) {
        const int hc = c << 7;
        #pragma unroll
        for (int i = 0; i < 4; ++i) {
            int lin = i * 512 + tid;
            int row = lin >> 4, kc = lin & 15;
            short8v v = *(const short8v*)(w1bt + w1base + (size_t)(hc + row) * 128 + kc * 8);
            *(short8v*)(W1t + row * 136 + kc * 8) = v;
        }
        #pragma unroll
        for (int i = 0; i < 4; ++i) {
            int lin = i * 512 + tid;
            int row = lin >> 4, kc = lin & 15;
            short8v v = *(const short8v*)(w2bt + w2base + (size_t)row * 512 + hc + kc * 8);
            *(short8v*)(W2t + row * 136 + kc * 8) = v;
        }
        __syncthreads();

        // ---- layer 1: H = relu(X @ W1 + b1), this 128-wide hid chunk ----
        f32x4 hacc[2][4];
        #pragma unroll
        for (int mi = 0; mi < 2; ++mi)
            #pragma unroll
            for (int ni = 0; ni < 4; ++ni)
                hacc[mi][ni] = (f32x4){0.f, 0.f, 0.f, 0.f};

        #pragma unroll
        for (int kk = 0; kk < 4; ++kk) {
            short8v a0 = *(const short8v*)(Xs + (wm * 32 +      l16) * 136 + kk * 32 + lg * 8);
            short8v a1 = *(const short8v*)(Xs + (wm * 32 + 16 + l16) * 136 + kk * 32 + lg * 8);
            #pragma unroll
            for (int ni = 0; ni < 4; ++ni) {
                short8v bfr = *(const short8v*)(W1t + (wn * 64 + ni * 16 + l16) * 136 + kk * 32 + lg * 8);
                hacc[0][ni] = __builtin_amdgcn_mfma_f32_16x16x32_bf16(a0, bfr, hacc[0][ni], 0, 0, 0);
                hacc[1][ni] = __builtin_amdgcn_mfma_f32_16x16x32_bf16(a1, bfr, hacc[1][ni], 0, 0, 0);
            }
        }
        #pragma unroll
        for (int ni = 0; ni < 4; ++ni) {
            float b1v = b1[e * 512 + hc + wn * 64 + ni * 16 + l16];
            #pragma unroll
            for (int mi = 0; mi < 2; ++mi) {
                #pragma unroll
                for (int r = 0; r < 4; ++r) {
                    float v = fmaxf(hacc[mi][ni][r] + b1v, 0.f);
                    Hs[(wm * 32 + mi * 16 + lg * 4 + r) * 136 + wn * 64 + ni * 16 + l16] =
                        (short)f2bf(v);
                }
            }
        }
        __syncthreads();

        // ---- layer 2: Y += H_chunk @ W2[hc:hc+128, :] ----
        #pragma unroll
        for (int kk = 0; kk < 4; ++kk) {
            short8v a0 = *(const short8v*)(Hs + (wm * 32 +      l16) * 136 + kk * 32 + lg * 8);
            short8v a1 = *(const short8v*)(Hs + (wm * 32 + 16 + l16) * 136 + kk * 32 + lg * 8);
            #pragma unroll
            for (int ni = 0; ni < 4; ++ni) {
                short8v bfr = *(const short8v*)(W2t + (wn * 64 + ni * 16 + l16) * 136 + kk * 32 + lg * 8);
                yacc[0][ni] = __builtin_amdgcn_mfma_f32_16x16x32_bf16(a0, bfr, yacc[0][ni], 0, 0, 0);
                yacc[1][ni] = __builtin_amdgcn_mfma_f32_16x16x32_bf16(a1, bfr, yacc[1][ni], 0, 0, 0);
            }
        }
        __syncthreads();
    }

    #pragma unroll
    for (int ni = 0; ni < 4; ++ni) {
        int d = wn * 64 + ni * 16 + l16;
        float b2v = b2[e * 128 + d];
        #pragma unroll
        for (int mi = 0; mi < 2; ++mi) {
            #pragma unroll
            for (int r = 0; r < 4; ++r) {
                int m = wm * 32 + mi * 16 + lg * 4 + r;
                pair_y[(size_t)(p0 + m) * 128 + d] = yacc[mi][ni][r] + b2v;
            }
        }
    }
}

// ---------------- combine: out[t] = p0*y0 + p1*y1 (NCHW store) ----------------
__global__ __launch_bounds__(256) void combine_kernel(
    const float* __restrict__ pair_y, const int* __restrict__ slot_of,
    const float* __restrict__ top_prob, float* __restrict__ out)
{
    __shared__ float ob[64][129];
    const int blk = blockIdx.x;               // 512
    const int b = blk >> 4;
    const int hw0 = (blk & 15) << 6;
    const int tid = threadIdx.x;
    #pragma unroll
    for (int i = 0; i < 32; ++i) {
        int lin = i * 256 + tid;
        int tl = lin >> 7, d = lin & 127;
        int t = b * 1024 + hw0 + tl;
        int s0 = slot_of[t * 2], s1 = slot_of[t * 2 + 1];
        float p0 = top_prob[t * 2], p1 = top_prob[t * 2 + 1];
        ob[tl][d] = p0 * pair_y[(size_t)s0 * 128 + d] + p1 * pair_y[(size_t)s1 * 128 + d];
    }
    __syncthreads();
    #pragma unroll
    for (int i = 0; i < 32; ++i) {
        int lin = i * 256 + tid;
        int d = lin >> 6, hwl = lin & 63;
        out[((size_t)b * 128 + d) * 1024 + hw0 + hwl] = ob[hwl][d];
    }
}

// ---------------- fallback per-token expert kernel ----------------------------
__global__ __launch_bounds__(256) void moe_expert_kernel(
    const float* __restrict__ x,
    const int* __restrict__ top_idx, const float* __restrict__ top_prob,
    const float* __restrict__ w1, const float* __restrict__ b1,
    const float* __restrict__ w2, const float* __restrict__ b2,
    float* __restrict__ out)
{
    __shared__ float xsB[128];
    __shared__ float hb[512];

    const int tid = threadIdx.x;
    const int t = blockIdx.x;
    const int b = t >> 10, hw = t & 1023;

    if (tid < 128)
        xsB[tid] = x[((size_t)b * 128 + tid) * NHW + hw];
    __syncthreads();

    float oacc = 0.f;
    #pragma unroll
    for (int k = 0; k < 2; ++k) {
        const int e = top_idx[t * 2 + k];
        const float pw = top_prob[t * 2 + k];
        const float* W1 = w1 + (size_t)e * (128 * 512);
        float a0 = 0.f, a1 = 0.f;
        for (int d = 0; d < 128; ++d) {
            float xv = xsB[d];
            a0 = fmaf(xv, W1[d * 512 + tid], a0);
            a1 = fmaf(xv, W1[d * 512 + tid + 256], a1);
        }
        hb[tid]       = fmaxf(a0 + b1[e * 512 + tid], 0.f);
        hb[tid + 256] = fmaxf(a1 + b1[e * 512 + tid + 256], 0.f);
        __syncthreads();
        if (tid < 128) {
            const float* W2 = w2 + (size_t)e * (512 * 128);
            float a = 0.f;
            for (int h = 0; h < 512; ++h)
                a = fmaf(hb[h], W2[h * 128 + tid], a);
            oacc = fmaf(pw, a + b2[e * 128 + tid], oacc);
        }
        __syncthreads();
    }
    if (tid < 128)
        out[((size_t)b * 128 + tid) * NHW + hw] = oacc;
}

// ---------------- host launch -------------------------------------------------
extern "C" void kernel_launch(void* const* d_in, const int* in_sizes, int n_in,
                              void* d_out, int out_size, void* d_ws, size_t ws_size,
                              hipStream_t stream) {
    const float* x       = (const float*)d_in[0];
    const float* gate_w  = (const float*)d_in[1];
    const float* gate_b  = (const float*)d_in[2];
    const float* noise_w = (const float*)d_in[3];
    const float* noise_b = (const float*)d_in[4];
    const float* w1      = (const float*)d_in[5];
    const float* b1      = (const float*)d_in[6];
    const float* w2      = (const float*)d_in[7];
    const float* b2      = (const float*)d_in[8];

    float* out   = (float*)d_out;                   // [32,128,32,32]
    float* gates = out + (size_t)NB * NC * NHW;     // [T,16]

    // workspace layout (byte offsets)
    const size_t OFF_CNT    = 0;          // 16 ints
    const size_t OFF_POFF   = 1024;       // 16 ints
    const size_t OFF_TOTAL  = 2048;       // 1 int
    const size_t OFF_B2E    = 4096;       // 544 ints
    const size_t OFF_B2C    = 8192;       // 544 ints
    const size_t OFF_TIDX   = 12288;      // T*2 ints
    const size_t OFF_RANK   = OFF_TIDX + (size_t)NT * 2 * 4;
    const size_t OFF_SLOT   = OFF_RANK + (size_t)NT * 2 * 4;
    const size_t OFF_PROB   = OFF_SLOT + (size_t)NT * 2 * 4;
    const size_t OFF_XTB    = OFF_PROB + (size_t)NT * 2 * 4;
    const size_t OFF_W1BT   = OFF_XTB + (size_t)NT * 128 * 2;
    const size_t OFF_W2BT   = OFF_W1BT + (size_t)NE * 512 * 128 * 2;
    const size_t OFF_PTOK   = OFF_W2BT + (size_t)NE * 128 * 512 * 2;
    const size_t NPAIR_PAD  = 67584;
    const size_t OFF_PAIRY  = OFF_PTOK + NPAIR_PAD * 4;
    const size_t NEED       = OFF_PAIRY + NPAIR_PAD * 128 * 4;

    char* ws = (char*)d_ws;
    int*   cnt      = (int*)(ws + OFF_CNT);
    int*   poff     = (int*)(ws + OFF_POFF);
    int*   total_ch = (int*)(ws + OFF_TOTAL);
    int*   blk2e    = (int*)(ws + OFF_B2E);
    int*   blk2c    = (int*)(ws + OFF_B2C);
    int*   top_idx  = (int*)(ws + OFF_TIDX);
    int*   rank     = (int*)(ws + OFF_RANK);
    int*   slot_of  = (int*)(ws + OFF_SLOT);
    float* top_prob = (float*)(ws + OFF_PROB);
    unsigned short* xtb  = (unsigned short*)(ws + OFF_XTB);
    unsigned short* w1bt = (unsigned short*)(ws + OFF_W1BT);
    unsigned short* w2bt = (unsigned short*)(ws + OFF_W2BT);
    int*   pair_tok = (int*)(ws + OFF_PTOK);
    float* pair_y   = (float*)(ws + OFF_PAIRY);

    const int use_new = (ws_size >= NEED) ? 1 : 0;

    if (use_new)
        hipMemsetAsync(cnt, 0, 16 * sizeof(int), stream);

    moe_gate_kernel<<<NT / 64, 256, 0, stream>>>(
        x, gate_w, gate_b, noise_w, noise_b,
        gates, top_idx, top_prob, rank, cnt, use_new);

    if (use_new) {
        // x[b][128][1024] -> xtb[b*1024+hw][128] bf16
        transpose_convert_kernel<<<NB * 2 * 16, 256, 0, stream>>>(x, xtb, 128, 1024);
        // w1[e][128][512] -> w1bt[e][512][128] ; w2[e][512][128] -> w2bt[e][128][512]
        transpose_convert_kernel<<<NE * 2 * 8, 256, 0, stream>>>(w1, w1bt, 128, 512);
        transpose_convert_kernel<<<NE * 8 * 2, 256, 0, stream>>>(w2, w2bt, 512, 128);
        scan_kernel<<<1, 256, 0, stream>>>(cnt, poff, blk2e, blk2c, total_ch, pair_tok);
        scatter_kernel<<<NT * 2 / 256, 256, 0, stream>>>(top_idx, rank, poff, pair_tok, slot_of);
        moe_mfma_kernel<<<528, 512, 0, stream>>>(
            xtb, pair_tok, blk2e, blk2c, poff, total_ch,
            w1bt, b1, w2bt, b2, pair_y);
        combine_kernel<<<512, 256, 0, stream>>>(pair_y, slot_of, top_prob, out);
    } else {
        moe_expert_kernel<<<NT, 256, 0, stream>>>(
            x, top_idx, top_prob, w1, b1, w2, b2, out);
    }
}

// Round 5
// 119.919 us; speedup vs baseline: 2.6054x; 2.4842x over previous
//
#include <hip/hip_runtime.h>
#include <stdint.h>

// Problem constants (fixed by the reference)
#define NB       32
#define NC       128
#define NHW      1024            // H*W
#define NT       32768           // tokens
#define NE       16
#define NHID     512

typedef __attribute__((ext_vector_type(8))) short short8v;   // 8 x bf16 (4 VGPRs)
typedef __attribute__((ext_vector_type(4))) float f32x4;

__device__ __forceinline__ unsigned short f2bf(float f) {
    uint32_t u = __float_as_uint(f);
    uint32_t r = u + 0x7fffu + ((u >> 16) & 1u);   // RNE (finite values)
    return (unsigned short)(r >> 16);
}

// ---------------- Threefry-2x32, 20 rounds (JAX) ----------------
__device__ __forceinline__ uint32_t rotl32(uint32_t x, uint32_t d) {
    return (x << d) | (x >> (32u - d));
}

__device__ __forceinline__ void threefry2x32_20(uint32_t k0, uint32_t k1,
                                                uint32_t& x0, uint32_t& x1) {
    const uint32_t ks0 = k0, ks1 = k1, ks2 = k0 ^ k1 ^ 0x1BD11BDAu;
    x0 += ks0; x1 += ks1;
#define TFR(r) { x0 += x1; x1 = rotl32(x1, r); x1 ^= x0; }
    TFR(13u) TFR(15u) TFR(26u) TFR(6u)
    x0 += ks1; x1 += ks2 + 1u;
    TFR(17u) TFR(29u) TFR(16u) TFR(24u)
    x0 += ks2; x1 += ks0 + 2u;
    TFR(13u) TFR(15u) TFR(26u) TFR(6u)
    x0 += ks0; x1 += ks1 + 3u;
    TFR(17u) TFR(29u) TFR(16u) TFR(24u)
    x0 += ks1; x1 += ks2 + 4u;
    TFR(13u) TFR(15u) TFR(26u) TFR(6u)
    x0 += ks2; x1 += ks0 + 5u;
#undef TFR
}

__device__ __forceinline__ float erfinv_xla_f32(float x) {
    float w = -log1pf(-x * x);
    float p;
    if (w < 5.0f) {
        w = w - 2.5f;
        p = 2.81022636e-08f;
        p = fmaf(p, w, 3.43273939e-07f);
        p = fmaf(p, w, -3.5233877e-06f);
        p = fmaf(p, w, -4.39150654e-06f);
        p = fmaf(p, w, 0.00021858087f);
        p = fmaf(p, w, -0.00125372503f);
        p = fmaf(p, w, -0.00417768164f);
        p = fmaf(p, w, 0.246640727f);
        p = fmaf(p, w, 1.50140941f);
    } else {
        w = sqrtf(w) - 3.0f;
        p = -0.000200214257f;
        p = fmaf(p, w, 0.000100950558f);
        p = fmaf(p, w, 0.00134934322f);
        p = fmaf(p, w, -0.00367342844f);
        p = fmaf(p, w, 0.00573950773f);
        p = fmaf(p, w, -0.0076224613f);
        p = fmaf(p, w, 0.00943887047f);
        p = fmaf(p, w, 1.00167406f);
        p = fmaf(p, w, 2.83297682f);
    }
    return p * x;
}

__device__ __forceinline__ float jax_noise_elem(uint32_t i) {
    uint32_t x0 = 0u, x1 = i;
    threefry2x32_20(0u, 42u, x0, x1);
    uint32_t bits = x0 ^ x1;
    float f = __uint_as_float(0x3f800000u | (bits >> 9)) - 1.0f;
    const float lo = -0.99999994f;
    float u = f * 2.0f + lo;
    u = fmaxf(lo, u);
    return 1.41421354f * erfinv_xla_f32(u);
}

// ---------------- Kernel A: gating + noise + top-2 ----------------------------
// 4 threads per token, 64 tokens/block. Rank assignment is hierarchical:
// LDS histogram per block + ONE global atomicAdd per (block, expert) -> base.
// (65536 contended global atomics was the 200 µs wall in rounds 2-4.)
__global__ __launch_bounds__(256) void moe_gate_kernel(
    const float* __restrict__ x,
    const float* __restrict__ gate_w, const float* __restrict__ gate_b,
    const float* __restrict__ noise_w, const float* __restrict__ noise_b,
    float* __restrict__ gates_out,        // [T,16] region of d_out
    int*   __restrict__ top_idx,          // [T,2]
    float* __restrict__ top_prob,         // [T,2]
    int*   __restrict__ rank,             // [T,2]
    int*   __restrict__ cnt,              // [16]
    int do_new)
{
    __shared__ float lw[32 * 160];        // [ci=32][q=4][40]; e<16 gate, e>=16 noise
    __shared__ int   lcnt[16];            // block-local expert histogram
    __shared__ int   lbase[16];           // global base for this block

    const int tid = threadIdx.x;
    const int tl  = tid >> 2;                     // token within block (0..63)
    const int q   = tid & 3;                      // channel quarter
    const int t   = blockIdx.x * 64 + tl;         // global token
    const int b   = t >> 10, hw = t & 1023;

    if (tid < 16) lcnt[tid] = 0;

    // stage weights: lw[ci][q][e] = w[(q*32+ci)*16 + e]
    for (int idx = tid; idx < 4096; idx += 256) {
        int ci = idx >> 7;
        int r  = idx & 127;
        int qq = r >> 5, e = r & 31;
        int c  = qq * 32 + ci;
        float v = (e < 16) ? gate_w[c * 16 + e] : noise_w[c * 16 + (e - 16)];
        lw[ci * 160 + qq * 40 + e] = v;
    }
    __syncthreads();

    // partial dot over this thread's 32 channels
    float acc[32];
    #pragma unroll
    for (int e = 0; e < 32; ++e) acc[e] = 0.f;

    const float* xq = x + (size_t)b * (NC * NHW) + (size_t)(q * 32) * NHW + hw;
    const float* wq = lw + q * 40;
    #pragma unroll 4
    for (int ci = 0; ci < 32; ++ci) {
        float xv = xq[(size_t)ci << 10];
        const f32x4* wr = (const f32x4*)(wq + ci * 160);
        #pragma unroll
        for (int j = 0; j < 8; ++j) {
            f32x4 w4 = wr[j];
            #pragma unroll
            for (int k = 0; k < 4; ++k)
                acc[j * 4 + k] = fmaf(xv, w4[k], acc[j * 4 + k]);
        }
    }

    // butterfly reduce across the 4 q-lanes (q = lane bits 0-1)
    #pragma unroll
    for (int e = 0; e < 32; ++e) {
        acc[e] += __shfl_xor(acc[e], 1);
        acc[e] += __shfl_xor(acc[e], 2);
    }

    // this lane finishes experts e = q*4 .. q*4+3
    float lg[4];
    #pragma unroll
    for (int j = 0; j < 4; ++j) {
        int e = q * 4 + j;
        float g  = acc[e] + gate_b[e];
        float an = acc[16 + e] + noise_b[e];
        float sd = fmaxf(an, 0.f) + log1pf(expf(-fabsf(an)));
        float nz = jax_noise_elem((uint32_t)t * 16u + (uint32_t)e);
        lg[j] = fmaf(nz, sd, g);
    }

    // local top-2 (value desc, index asc — matches lax.top_k stability)
    float v1 = lg[0], v2 = -INFINITY;
    int   i1 = q * 4, i2 = 0x7fffffff;
    #pragma unroll
    for (int j = 1; j < 4; ++j) {
        float v = lg[j]; int e = q * 4 + j;
        if (v > v1) { v2 = v1; i2 = i1; v1 = v; i1 = e; }
        else if (v > v2) { v2 = v; i2 = e; }
    }
    // merge across q-lanes
    #pragma unroll
    for (int m = 1; m <= 2; m <<= 1) {
        float pv1 = __shfl_xor(v1, m), pv2 = __shfl_xor(v2, m);
        int   pi1 = __shfl_xor(i1, m), pi2 = __shfl_xor(i2, m);
        bool pBest = (pv1 > v1) || (pv1 == v1 && pi1 < i1);
        float c2v; int c2i;                 // the loser of the top-1 contest
        if (pBest) { c2v = v1;  c2i = i1;  v1 = pv1; i1 = pi1;
                     if (!((c2v > pv2) || (c2v == pv2 && c2i < pi2))) { c2v = pv2; c2i = pi2; }
        } else     { c2v = pv1; c2i = pi1;
                     if (!((c2v > v2)  || (c2v == v2  && c2i < i2)))  { c2v = v2;  c2i = i2;  }
        }
        v2 = c2v; i2 = c2i;
    }

    float qq = expf(v2 - v1);
    float s  = 1.0f + qq;
    float p1 = 1.0f / s;
    float p2 = qq / s;

    // write this lane's 4 gate entries (wave stores are fully contiguous)
    f32x4 g4;
    #pragma unroll
    for (int j = 0; j < 4; ++j) {
        int e = q * 4 + j;
        g4[j] = (e == i1) ? p1 : ((e == i2) ? p2 : 0.f);
    }
    *(f32x4*)(gates_out + (size_t)t * 16 + q * 4) = g4;

    int r1 = 0, r2 = 0;
    if (q == 0) {
        top_idx[t * 2 + 0] = i1;  top_idx[t * 2 + 1] = i2;
        top_prob[t * 2 + 0] = p1; top_prob[t * 2 + 1] = p2;
        if (do_new) {
            r1 = atomicAdd(&lcnt[i1], 1);     // LDS atomics: intra-block only
            r2 = atomicAdd(&lcnt[i2], 1);
        }
    }
    if (do_new) {
        __syncthreads();
        if (tid < 16) lbase[tid] = atomicAdd(&cnt[tid], lcnt[tid]);  // 16/block
        __syncthreads();
        if (q == 0) {
            rank[t * 2 + 0] = lbase[i1] + r1;
            rank[t * 2 + 1] = lbase[i2] + r2;
        }
    }
}

// ---------------- transpose + f32->bf16 convert: dst[e][c][r] = src[e][r][c] --
__global__ __launch_bounds__(256) void transpose_convert_kernel(
    const float* __restrict__ src, unsigned short* __restrict__ dst, int R, int C)
{
    __shared__ float ts[64][65];
    const int nr = R >> 6, ncc = C >> 6;
    const int blk = blockIdx.x;
    const int e = blk / (nr * ncc);
    const int rem = blk % (nr * ncc);
    const int rt = rem / ncc, ct = rem % ncc;
    const float* S = src + (size_t)e * R * C + (size_t)(rt * 64) * C + ct * 64;
    unsigned short* D = dst + (size_t)e * R * C + (size_t)(ct * 64) * R + rt * 64;
    const int tid = threadIdx.x;
    #pragma unroll
    for (int i = 0; i < 16; ++i) {
        int lin = i * 256 + tid;
        int r = lin >> 6, c = lin & 63;
        ts[r][c] = S[(size_t)r * C + c];
    }
    __syncthreads();
    #pragma unroll
    for (int i = 0; i < 16; ++i) {
        int lin = i * 256 + tid;
        int c = lin >> 6, r = lin & 63;
        D[(size_t)c * R + r] = f2bf(ts[r][c]);
    }
}

// ---------------- scan: padded offsets, block->(e,chunk) table, pad fill ------
__global__ __launch_bounds__(256) void scan_kernel(
    const int* __restrict__ cnt,
    int* __restrict__ poff, int* __restrict__ blk2e,
    int* __restrict__ blk2chunk, int* __restrict__ total_chunks,
    int* __restrict__ pair_tok)
{
    __shared__ int snch[16];
    __shared__ int scum[17];
    __shared__ int spoff[16];
    const int tid = threadIdx.x;
    if (tid < 16) snch[tid] = (cnt[tid] + 127) >> 7;
    __syncthreads();
    if (tid == 0) {
        int cc = 0, off = 0;
        for (int e = 0; e < 16; ++e) {
            scum[e] = cc; spoff[e] = off;
            cc += snch[e]; off += snch[e] << 7;
        }
        scum[16] = cc;
        *total_chunks = cc;
    }
    __syncthreads();
    const int tot = scum[16];
    for (int idx = tid; idx < tot; idx += 256) {
        int e = 0;
        #pragma unroll
        for (int k = 0; k < 15; ++k)
            if (idx >= scum[k + 1]) e = k + 1;
        blk2e[idx] = e;
        blk2chunk[idx] = idx - scum[e];
    }
    if (tid < 16) poff[tid] = spoff[tid];
    for (int e = 0; e < 16; ++e) {
        int start = spoff[e] + cnt[e];
        int end   = spoff[e] + (snch[e] << 7);
        for (int i = start + tid; i < end; i += 256)
            pair_tok[i] = -1;
    }
}

// ---------------- scatter pairs into expert bins ------------------------------
__global__ __launch_bounds__(256) void scatter_kernel(
    const int* __restrict__ top_idx, const int* __restrict__ rank,
    const int* __restrict__ poff, int* __restrict__ pair_tok,
    int* __restrict__ slot_of)
{
    int i = blockIdx.x * 256 + threadIdx.x;   // 0..65535
    int t = i >> 1;
    int e = top_idx[i];
    int slot = poff[e] + rank[i];
    pair_tok[slot] = t;
    slot_of[i] = slot;
}

// ---------------- grouped MFMA MLP: 1 block = (expert, 128 pairs) -------------
__global__ __launch_bounds__(512, 1) void moe_mfma_kernel(
    const unsigned short* __restrict__ xtb,
    const int* __restrict__ pair_tok, const int* __restrict__ blk2e,
    const int* __restrict__ blk2chunk, const int* __restrict__ poff,
    const int* __restrict__ total_chunks,
    const unsigned short* __restrict__ w1bt,   // [E][HID][D] bf16
    const float* __restrict__ b1,
    const unsigned short* __restrict__ w2bt,   // [E][D][HID] bf16
    const float* __restrict__ b2,
    float* __restrict__ pair_y)                // [Ppad][128] f32
{
    __shared__ short Xs[128 * 136];
    __shared__ short Hs[128 * 136];
    __shared__ short W1t[128 * 136];   // rows: h_local, cols: d
    __shared__ short W2t[128 * 136];   // rows: d, cols: h_local
    __shared__ int   ptoks[128];

    const int blk = blockIdx.x;
    if (blk >= *total_chunks) return;
    const int e  = blk2e[blk];
    const int p0 = poff[e] + (blk2chunk[blk] << 7);
    const int tid  = threadIdx.x;
    const int lane = tid & 63;
    const int wid  = tid >> 6;       // 0..7
    const int wm   = wid >> 1;       // 0..3 -> m0 = wm*32
    const int wn   = wid & 1;        // 0..1 -> n0 = wn*64
    const int l16  = lane & 15;
    const int lg   = lane >> 4;      // 0..3

    if (tid < 128) ptoks[tid] = pair_tok[p0 + tid];
    __syncthreads();

    #pragma unroll
    for (int i = 0; i < 4; ++i) {
        int lin = i * 512 + tid;              // 0..2047
        int row = lin >> 4, kc = lin & 15;
        int tok = ptoks[row];
        short8v v = {};
        if (tok >= 0)
            v = *(const short8v*)(xtb + (size_t)tok * 128 + kc * 8);
        *(short8v*)(Xs + row * 136 + kc * 8) = v;
    }

    f32x4 yacc[2][4];
    #pragma unroll
    for (int mi = 0; mi < 2; ++mi)
        #pragma unroll
        for (int ni = 0; ni < 4; ++ni)
            yacc[mi][ni] = (f32x4){0.f, 0.f, 0.f, 0.f};

    const size_t w1base = (size_t)e * 512 * 128;
    const size_t w2base = (size_t)e * 128 * 512;

    for (int c = 0; c < 4; ++c) {
        const int hc = c << 7;
        #pragma unroll
        for (int i = 0; i < 4; ++i) {
            int lin = i * 512 + tid;
            int row = lin >> 4, kc = lin & 15;
            short8v v = *(const short8v*)(w1bt + w1base + (size_t)(hc + row) * 128 + kc * 8);
            *(short8v*)(W1t + row * 136 + kc * 8) = v;
        }
        #pragma unroll
        for (int i = 0; i < 4; ++i) {
            int lin = i * 512 + tid;
            int row = lin >> 4, kc = lin & 15;
            short8v v = *(const short8v*)(w2bt + w2base + (size_t)row * 512 + hc + kc * 8);
            *(short8v*)(W2t + row * 136 + kc * 8) = v;
        }
        __syncthreads();

        // ---- layer 1: H = relu(X @ W1 + b1), this 128-wide hid chunk ----
        f32x4 hacc[2][4];
        #pragma unroll
        for (int mi = 0; mi < 2; ++mi)
            #pragma unroll
            for (int ni = 0; ni < 4; ++ni)
                hacc[mi][ni] = (f32x4){0.f, 0.f, 0.f, 0.f};

        #pragma unroll
        for (int kk = 0; kk < 4; ++kk) {
            short8v a0 = *(const short8v*)(Xs + (wm * 32 +      l16) * 136 + kk * 32 + lg * 8);
            short8v a1 = *(const short8v*)(Xs + (wm * 32 + 16 + l16) * 136 + kk * 32 + lg * 8);
            #pragma unroll
            for (int ni = 0; ni < 4; ++ni) {
                short8v bfr = *(const short8v*)(W1t + (wn * 64 + ni * 16 + l16) * 136 + kk * 32 + lg * 8);
                hacc[0][ni] = __builtin_amdgcn_mfma_f32_16x16x32_bf16(a0, bfr, hacc[0][ni], 0, 0, 0);
                hacc[1][ni] = __builtin_amdgcn_mfma_f32_16x16x32_bf16(a1, bfr, hacc[1][ni], 0, 0, 0);
            }
        }
        #pragma unroll
        for (int ni = 0; ni < 4; ++ni) {
            float b1v = b1[e * 512 + hc + wn * 64 + ni * 16 + l16];
            #pragma unroll
            for (int mi = 0; mi < 2; ++mi) {
                #pragma unroll
                for (int r = 0; r < 4; ++r) {
                    float v = fmaxf(hacc[mi][ni][r] + b1v, 0.f);
                    Hs[(wm * 32 + mi * 16 + lg * 4 + r) * 136 + wn * 64 + ni * 16 + l16] =
                        (short)f2bf(v);
                }
            }
        }
        __syncthreads();

        // ---- layer 2: Y += H_chunk @ W2[hc:hc+128, :] ----
        #pragma unroll
        for (int kk = 0; kk < 4; ++kk) {
            short8v a0 = *(const short8v*)(Hs + (wm * 32 +      l16) * 136 + kk * 32 + lg * 8);
            short8v a1 = *(const short8v*)(Hs + (wm * 32 + 16 + l16) * 136 + kk * 32 + lg * 8);
            #pragma unroll
            for (int ni = 0; ni < 4; ++ni) {
                short8v bfr = *(const short8v*)(W2t + (wn * 64 + ni * 16 + l16) * 136 + kk * 32 + lg * 8);
                yacc[0][ni] = __builtin_amdgcn_mfma_f32_16x16x32_bf16(a0, bfr, yacc[0][ni], 0, 0, 0);
                yacc[1][ni] = __builtin_amdgcn_mfma_f32_16x16x32_bf16(a1, bfr, yacc[1][ni], 0, 0, 0);
            }
        }
        __syncthreads();
    }

    #pragma unroll
    for (int ni = 0; ni < 4; ++ni) {
        int d = wn * 64 + ni * 16 + l16;
        float b2v = b2[e * 128 + d];
        #pragma unroll
        for (int mi = 0; mi < 2; ++mi) {
            #pragma unroll
            for (int r = 0; r < 4; ++r) {
                int m = wm * 32 + mi * 16 + lg * 4 + r;
                pair_y[(size_t)(p0 + m) * 128 + d] = yacc[mi][ni][r] + b2v;
            }
        }
    }
}

// ---------------- combine: out[t] = p0*y0 + p1*y1 (NCHW store) ----------------
__global__ __launch_bounds__(256) void combine_kernel(
    const float* __restrict__ pair_y, const int* __restrict__ slot_of,
    const float* __restrict__ top_prob, float* __restrict__ out)
{
    __shared__ float ob[64][129];
    const int blk = blockIdx.x;               // 512
    const int b = blk >> 4;
    const int hw0 = (blk & 15) << 6;
    const int tid = threadIdx.x;
    #pragma unroll
    for (int i = 0; i < 32; ++i) {
        int lin = i * 256 + tid;
        int tl = lin >> 7, d = lin & 127;
        int t = b * 1024 + hw0 + tl;
        int s0 = slot_of[t * 2], s1 = slot_of[t * 2 + 1];
        float p0 = top_prob[t * 2], p1 = top_prob[t * 2 + 1];
        ob[tl][d] = p0 * pair_y[(size_t)s0 * 128 + d] + p1 * pair_y[(size_t)s1 * 128 + d];
    }
    __syncthreads();
    #pragma unroll
    for (int i = 0; i < 32; ++i) {
        int lin = i * 256 + tid;
        int d = lin >> 6, hwl = lin & 63;
        out[((size_t)b * 128 + d) * 1024 + hw0 + hwl] = ob[hwl][d];
    }
}

// ---------------- fallback per-token expert kernel ----------------------------
__global__ __launch_bounds__(256) void moe_expert_kernel(
    const float* __restrict__ x,
    const int* __restrict__ top_idx, const float* __restrict__ top_prob,
    const float* __restrict__ w1, const float* __restrict__ b1,
    const float* __restrict__ w2, const float* __restrict__ b2,
    float* __restrict__ out)
{
    __shared__ float xsB[128];
    __shared__ float hb[512];

    const int tid = threadIdx.x;
    const int t = blockIdx.x;
    const int b = t >> 10, hw = t & 1023;

    if (tid < 128)
        xsB[tid] = x[((size_t)b * 128 + tid) * NHW + hw];
    __syncthreads();

    float oacc = 0.f;
    #pragma unroll
    for (int k = 0; k < 2; ++k) {
        const int e = top_idx[t * 2 + k];
        const float pw = top_prob[t * 2 + k];
        const float* W1 = w1 + (size_t)e * (128 * 512);
        float a0 = 0.f, a1 = 0.f;
        for (int d = 0; d < 128; ++d) {
            float xv = xsB[d];
            a0 = fmaf(xv, W1[d * 512 + tid], a0);
            a1 = fmaf(xv, W1[d * 512 + tid + 256], a1);
        }
        hb[tid]       = fmaxf(a0 + b1[e * 512 + tid], 0.f);
        hb[tid + 256] = fmaxf(a1 + b1[e * 512 + tid + 256], 0.f);
        __syncthreads();
        if (tid < 128) {
            const float* W2 = w2 + (size_t)e * (512 * 128);
            float a = 0.f;
            for (int h = 0; h < 512; ++h)
                a = fmaf(hb[h], W2[h * 128 + tid], a);
            oacc = fmaf(pw, a + b2[e * 128 + tid], oacc);
        }
        __syncthreads();
    }
    if (tid < 128)
        out[((size_t)b * 128 + tid) * NHW + hw] = oacc;
}

// ---------------- host launch -------------------------------------------------
extern "C" void kernel_launch(void* const* d_in, const int* in_sizes, int n_in,
                              void* d_out, int out_size, void* d_ws, size_t ws_size,
                              hipStream_t stream) {
    const float* x       = (const float*)d_in[0];
    const float* gate_w  = (const float*)d_in[1];
    const float* gate_b  = (const float*)d_in[2];
    const float* noise_w = (const float*)d_in[3];
    const float* noise_b = (const float*)d_in[4];
    const float* w1      = (const float*)d_in[5];
    const float* b1      = (const float*)d_in[6];
    const float* w2      = (const float*)d_in[7];
    const float* b2      = (const float*)d_in[8];

    float* out   = (float*)d_out;                   // [32,128,32,32]
    float* gates = out + (size_t)NB * NC * NHW;     // [T,16]

    // workspace layout (byte offsets)
    const size_t OFF_CNT    = 0;          // 16 ints
    const size_t OFF_POFF   = 1024;       // 16 ints
    const size_t OFF_TOTAL  = 2048;       // 1 int
    const size_t OFF_B2E    = 4096;       // 544 ints
    const size_t OFF_B2C    = 8192;       // 544 ints
    const size_t OFF_TIDX   = 12288;      // T*2 ints
    const size_t OFF_RANK   = OFF_TIDX + (size_t)NT * 2 * 4;
    const size_t OFF_SLOT   = OFF_RANK + (size_t)NT * 2 * 4;
    const size_t OFF_PROB   = OFF_SLOT + (size_t)NT * 2 * 4;
    const size_t OFF_XTB    = OFF_PROB + (size_t)NT * 2 * 4;
    const size_t OFF_W1BT   = OFF_XTB + (size_t)NT * 128 * 2;
    const size_t OFF_W2BT   = OFF_W1BT + (size_t)NE * 512 * 128 * 2;
    const size_t OFF_PTOK   = OFF_W2BT + (size_t)NE * 128 * 512 * 2;
    const size_t NPAIR_PAD  = 67584;
    const size_t OFF_PAIRY  = OFF_PTOK + NPAIR_PAD * 4;
    const size_t NEED       = OFF_PAIRY + NPAIR_PAD * 128 * 4;

    char* ws = (char*)d_ws;
    int*   cnt      = (int*)(ws + OFF_CNT);
    int*   poff     = (int*)(ws + OFF_POFF);
    int*   total_ch = (int*)(ws + OFF_TOTAL);
    int*   blk2e    = (int*)(ws + OFF_B2E);
    int*   blk2c    = (int*)(ws + OFF_B2C);
    int*   top_idx  = (int*)(ws + OFF_TIDX);
    int*   rank     = (int*)(ws + OFF_RANK);
    int*   slot_of  = (int*)(ws + OFF_SLOT);
    float* top_prob = (float*)(ws + OFF_PROB);
    unsigned short* xtb  = (unsigned short*)(ws + OFF_XTB);
    unsigned short* w1bt = (unsigned short*)(ws + OFF_W1BT);
    unsigned short* w2bt = (unsigned short*)(ws + OFF_W2BT);
    int*   pair_tok = (int*)(ws + OFF_PTOK);
    float* pair_y   = (float*)(ws + OFF_PAIRY);

    const int use_new = (ws_size >= NEED) ? 1 : 0;

    if (use_new)
        hipMemsetAsync(cnt, 0, 16 * sizeof(int), stream);

    moe_gate_kernel<<<NT / 64, 256, 0, stream>>>(
        x, gate_w, gate_b, noise_w, noise_b,
        gates, top_idx, top_prob, rank, cnt, use_new);

    if (use_new) {
        // x[b][128][1024] -> xtb[b*1024+hw][128] bf16
        transpose_convert_kernel<<<NB * 2 * 16, 256, 0, stream>>>(x, xtb, 128, 1024);
        // w1[e][128][512] -> w1bt[e][512][128] ; w2[e][512][128] -> w2bt[e][128][512]
        transpose_convert_kernel<<<NE * 2 * 8, 256, 0, stream>>>(w1, w1bt, 128, 512);
        transpose_convert_kernel<<<NE * 8 * 2, 256, 0, stream>>>(w2, w2bt, 512, 128);
        scan_kernel<<<1, 256, 0, stream>>>(cnt, poff, blk2e, blk2c, total_ch, pair_tok);
        scatter_kernel<<<NT * 2 / 256, 256, 0, stream>>>(top_idx, rank, poff, pair_tok, slot_of);
        moe_mfma_kernel<<<528, 512, 0, stream>>>(
            xtb, pair_tok, blk2e, blk2c, poff, total_ch,
            w1bt, b1, w2bt, b2, pair_y);
        combine_kernel<<<512, 256, 0, stream>>>(pair_y, slot_of, top_prob, out);
    } else {
        moe_expert_kernel<<<NT, 256, 0, stream>>>(
            x, top_idx, top_prob, w1, b1, w2, b2, out);
    }
}

// Round 7
// 96.681 us; speedup vs baseline: 3.2316x; 1.2403x over previous
//
#include <hip/hip_runtime.h>
#include <stdint.h>

// Problem constants (fixed by the reference)
#define NB       32
#define NC       128
#define NHW      1024            // H*W
#define NT       32768           // tokens
#define NE       16
#define NHID     512

typedef __attribute__((ext_vector_type(8))) short short8v;   // 8 x bf16 (4 VGPRs)
typedef __attribute__((ext_vector_type(4))) float f32x4;

__device__ __forceinline__ unsigned short f2bf(float f) {
    uint32_t u = __float_as_uint(f);
    uint32_t r = u + 0x7fffu + ((u >> 16) & 1u);   // RNE (finite values)
    return (unsigned short)(r >> 16);
}
__device__ __forceinline__ float bf2f(unsigned short u) {
    return __uint_as_float(((uint32_t)u) << 16);
}

// async global->LDS, 16B per lane; LDS dest = base + lane*16 (linear),
// so swizzling is done on the per-lane GLOBAL source address (m173 pattern).
__device__ __forceinline__ void gll16(const void* g, void* l) {
    __builtin_amdgcn_global_load_lds(
        (const __attribute__((address_space(1))) uint32_t*)g,
        (__attribute__((address_space(3))) uint32_t*)l, 16, 0, 0);
}

#define WAIT_VMLGKM() asm volatile("s_waitcnt vmcnt(0) lgkmcnt(0)" ::: "memory")
#define WAIT_LGKM()   asm volatile("s_waitcnt lgkmcnt(0)" ::: "memory")
#define SBAR()        { asm volatile("" ::: "memory"); __builtin_amdgcn_s_barrier(); asm volatile("" ::: "memory"); }

// ---------------- Threefry-2x32, 20 rounds (JAX) ----------------
__device__ __forceinline__ uint32_t rotl32(uint32_t x, uint32_t d) {
    return (x << d) | (x >> (32u - d));
}

__device__ __forceinline__ void threefry2x32_20(uint32_t k0, uint32_t k1,
                                                uint32_t& x0, uint32_t& x1) {
    const uint32_t ks0 = k0, ks1 = k1, ks2 = k0 ^ k1 ^ 0x1BD11BDAu;
    x0 += ks0; x1 += ks1;
#define TFR(r) { x0 += x1; x1 = rotl32(x1, r); x1 ^= x0; }
    TFR(13u) TFR(15u) TFR(26u) TFR(6u)
    x0 += ks1; x1 += ks2 + 1u;
    TFR(17u) TFR(29u) TFR(16u) TFR(24u)
    x0 += ks2; x1 += ks0 + 2u;
    TFR(13u) TFR(15u) TFR(26u) TFR(6u)
    x0 += ks0; x1 += ks1 + 3u;
    TFR(17u) TFR(29u) TFR(16u) TFR(24u)
    x0 += ks1; x1 += ks2 + 4u;
    TFR(13u) TFR(15u) TFR(26u) TFR(6u)
    x0 += ks2; x1 += ks0 + 5u;
#undef TFR
}

__device__ __forceinline__ float erfinv_xla_f32(float x) {
    float w = -log1pf(-x * x);
    float p;
    if (w < 5.0f) {
        w = w - 2.5f;
        p = 2.81022636e-08f;
        p = fmaf(p, w, 3.43273939e-07f);
        p = fmaf(p, w, -3.5233877e-06f);
        p = fmaf(p, w, -4.39150654e-06f);
        p = fmaf(p, w, 0.00021858087f);
        p = fmaf(p, w, -0.00125372503f);
        p = fmaf(p, w, -0.00417768164f);
        p = fmaf(p, w, 0.246640727f);
        p = fmaf(p, w, 1.50140941f);
    } else {
        w = sqrtf(w) - 3.0f;
        p = -0.000200214257f;
        p = fmaf(p, w, 0.000100950558f);
        p = fmaf(p, w, 0.00134934322f);
        p = fmaf(p, w, -0.00367342844f);
        p = fmaf(p, w, 0.00573950773f);
        p = fmaf(p, w, -0.0076224613f);
        p = fmaf(p, w, 0.00943887047f);
        p = fmaf(p, w, 1.00167406f);
        p = fmaf(p, w, 2.83297682f);
    }
    return p * x;
}

__device__ __forceinline__ float jax_noise_elem(uint32_t i) {
    uint32_t x0 = 0u, x1 = i;
    threefry2x32_20(0u, 42u, x0, x1);
    uint32_t bits = x0 ^ x1;
    float f = __uint_as_float(0x3f800000u | (bits >> 9)) - 1.0f;
    const float lo = -0.99999994f;
    float u = f * 2.0f + lo;
    u = fmaxf(lo, u);
    return 1.41421354f * erfinv_xla_f32(u);
}

// ---------------- Kernel A: gating + noise + top-2 (+ xtb emit) ---------------
// 4 threads per token, 64 tokens/block. Hierarchical rank assignment
// (LDS histogram + 16 global atomics/block). Also writes xtb [T,128] bf16.
__global__ __launch_bounds__(256) void moe_gate_kernel(
    const float* __restrict__ x,
    const float* __restrict__ gate_w, const float* __restrict__ gate_b,
    const float* __restrict__ noise_w, const float* __restrict__ noise_b,
    float* __restrict__ gates_out,        // [T,16] region of d_out
    int*   __restrict__ top_idx,          // [T,2]
    float* __restrict__ top_prob,         // [T,2]
    int*   __restrict__ rank,             // [T,2]
    int*   __restrict__ cnt,              // [16]
    unsigned short* __restrict__ xtb,     // [T,128] bf16
    int do_new)
{
    __shared__ float lw[32 * 160];        // [ci=32][q=4][40]; e<16 gate, e>=16 noise
    __shared__ int   lcnt[16];
    __shared__ int   lbase[16];

    const int tid = threadIdx.x;
    const int tl  = tid >> 2;                     // token within block (0..63)
    const int q   = tid & 3;                      // channel quarter
    const int t   = blockIdx.x * 64 + tl;         // global token
    const int b   = t >> 10, hw = t & 1023;

    if (tid < 16) lcnt[tid] = 0;

    for (int idx = tid; idx < 4096; idx += 256) {
        int ci = idx >> 7;
        int r  = idx & 127;
        int qq = r >> 5, e = r & 31;
        int c  = qq * 32 + ci;
        float v = (e < 16) ? gate_w[c * 16 + e] : noise_w[c * 16 + (e - 16)];
        lw[ci * 160 + qq * 40 + e] = v;
    }
    __syncthreads();

    float acc[32];
    #pragma unroll
    for (int e = 0; e < 32; ++e) acc[e] = 0.f;

    unsigned short xh[32];
    const float* xq = x + (size_t)b * (NC * NHW) + (size_t)(q * 32) * NHW + hw;
    const float* wq = lw + q * 40;
    #pragma unroll 4
    for (int ci = 0; ci < 32; ++ci) {
        float xv = xq[(size_t)ci << 10];
        xh[ci] = f2bf(xv);
        const f32x4* wr = (const f32x4*)(wq + ci * 160);
        #pragma unroll
        for (int j = 0; j < 8; ++j) {
            f32x4 w4 = wr[j];
            #pragma unroll
            for (int k = 0; k < 4; ++k)
                acc[j * 4 + k] = fmaf(xv, w4[k], acc[j * 4 + k]);
        }
    }

    if (do_new) {
        #pragma unroll
        for (int j = 0; j < 4; ++j) {
            short8v v;
            #pragma unroll
            for (int k = 0; k < 8; ++k) v[k] = (short)xh[j * 8 + k];
            *(short8v*)(xtb + (size_t)t * 128 + q * 32 + j * 8) = v;
        }
    }

    #pragma unroll
    for (int e = 0; e < 32; ++e) {
        acc[e] += __shfl_xor(acc[e], 1);
        acc[e] += __shfl_xor(acc[e], 2);
    }

    float lg[4];
    #pragma unroll
    for (int j = 0; j < 4; ++j) {
        int e = q * 4 + j;
        float g  = acc[e] + gate_b[e];
        float an = acc[16 + e] + noise_b[e];
        float sd = fmaxf(an, 0.f) + log1pf(expf(-fabsf(an)));
        float nz = jax_noise_elem((uint32_t)t * 16u + (uint32_t)e);
        lg[j] = fmaf(nz, sd, g);
    }

    float v1 = lg[0], v2 = -INFINITY;
    int   i1 = q * 4, i2 = 0x7fffffff;
    #pragma unroll
    for (int j = 1; j < 4; ++j) {
        float v = lg[j]; int e = q * 4 + j;
        if (v > v1) { v2 = v1; i2 = i1; v1 = v; i1 = e; }
        else if (v > v2) { v2 = v; i2 = e; }
    }
    #pragma unroll
    for (int m = 1; m <= 2; m <<= 1) {
        float pv1 = __shfl_xor(v1, m), pv2 = __shfl_xor(v2, m);
        int   pi1 = __shfl_xor(i1, m), pi2 = __shfl_xor(i2, m);
        bool pBest = (pv1 > v1) || (pv1 == v1 && pi1 < i1);
        float c2v; int c2i;
        if (pBest) { c2v = v1;  c2i = i1;  v1 = pv1; i1 = pi1;
                     if (!((c2v > pv2) || (c2v == pv2 && c2i < pi2))) { c2v = pv2; c2i = pi2; }
        } else     { c2v = pv1; c2i = pi1;
                     if (!((c2v > v2)  || (c2v == v2  && c2i < i2)))  { c2v = v2;  c2i = i2;  }
        }
        v2 = c2v; i2 = c2i;
    }

    float qq = expf(v2 - v1);
    float s  = 1.0f + qq;
    float p1 = 1.0f / s;
    float p2 = qq / s;

    f32x4 g4;
    #pragma unroll
    for (int j = 0; j < 4; ++j) {
        int e = q * 4 + j;
        g4[j] = (e == i1) ? p1 : ((e == i2) ? p2 : 0.f);
    }
    *(f32x4*)(gates_out + (size_t)t * 16 + q * 4) = g4;

    int r1 = 0, r2 = 0;
    if (q == 0) {
        top_idx[t * 2 + 0] = i1;  top_idx[t * 2 + 1] = i2;
        top_prob[t * 2 + 0] = p1; top_prob[t * 2 + 1] = p2;
        if (do_new) {
            r1 = atomicAdd(&lcnt[i1], 1);
            r2 = atomicAdd(&lcnt[i2], 1);
        }
    }
    if (do_new) {
        __syncthreads();
        if (tid < 16) lbase[tid] = atomicAdd(&cnt[tid], lcnt[tid]);
        __syncthreads();
        if (q == 0) {
            rank[t * 2 + 0] = lbase[i1] + r1;
            rank[t * 2 + 1] = lbase[i2] + r2;
        }
    }
}

// ---------------- transpose + f32->bf16 convert: dst[e][c][r] = src[e][r][c] --
__global__ __launch_bounds__(256) void transpose_convert_kernel(
    const float* __restrict__ src, unsigned short* __restrict__ dst, int R, int C)
{
    __shared__ float ts[64][65];
    const int nr = R >> 6, ncc = C >> 6;
    const int blk = blockIdx.x;
    const int e = blk / (nr * ncc);
    const int rem = blk % (nr * ncc);
    const int rt = rem / ncc, ct = rem % ncc;
    const float* S = src + (size_t)e * R * C + (size_t)(rt * 64) * C + ct * 64;
    unsigned short* D = dst + (size_t)e * R * C + (size_t)(ct * 64) * R + rt * 64;
    const int tid = threadIdx.x;
    #pragma unroll
    for (int i = 0; i < 16; ++i) {
        int lin = i * 256 + tid;
        int r = lin >> 6, c = lin & 63;
        ts[r][c] = S[(size_t)r * C + c];
    }
    __syncthreads();
    #pragma unroll
    for (int i = 0; i < 16; ++i) {
        int lin = i * 256 + tid;
        int c = lin >> 6, r = lin & 63;
        D[(size_t)c * R + r] = f2bf(ts[r][c]);
    }
}

// ---------------- scan: padded offsets, block->(e,chunk) table, pad fill ------
__global__ __launch_bounds__(256) void scan_kernel(
    const int* __restrict__ cnt,
    int* __restrict__ poff, int* __restrict__ blk2e,
    int* __restrict__ blk2chunk, int* __restrict__ total_chunks,
    int* __restrict__ pair_tok)
{
    __shared__ int snch[16];
    __shared__ int scum[17];
    __shared__ int spoff[16];
    const int tid = threadIdx.x;
    if (tid < 16) snch[tid] = (cnt[tid] + 127) >> 7;
    __syncthreads();
    if (tid == 0) {
        int cc = 0, off = 0;
        for (int e = 0; e < 16; ++e) {
            scum[e] = cc; spoff[e] = off;
            cc += snch[e]; off += snch[e] << 7;
        }
        scum[16] = cc;
        *total_chunks = cc;
    }
    __syncthreads();
    const int tot = scum[16];
    for (int idx = tid; idx < tot; idx += 256) {
        int e = 0;
        #pragma unroll
        for (int k = 0; k < 15; ++k)
            if (idx >= scum[k + 1]) e = k + 1;
        blk2e[idx] = e;
        blk2chunk[idx] = idx - scum[e];
    }
    if (tid < 16) poff[tid] = spoff[tid];
    for (int e = 0; e < 16; ++e) {
        int start = spoff[e] + cnt[e];
        int end   = spoff[e] + (snch[e] << 7);
        for (int i = start + tid; i < end; i += 256)
            pair_tok[i] = -1;
    }
}

// ---------------- scatter pairs into expert bins ------------------------------
__global__ __launch_bounds__(256) void scatter_kernel(
    const int* __restrict__ top_idx, const int* __restrict__ rank,
    const int* __restrict__ poff, int* __restrict__ pair_tok,
    int* __restrict__ slot_of)
{
    int i = blockIdx.x * 256 + threadIdx.x;   // 0..65535
    int t = i >> 1;
    int e = top_idx[i];
    int slot = poff[e] + rank[i];
    pair_tok[slot] = t;
    slot_of[i] = slot;
}

// ---------------- grouped MFMA MLP: 1 block = (expert, 128 pairs) -------------
// LDS = exactly 80 KB -> 2 blocks/CU. XOR-swizzled tiles (conflict-free
// ds_read_b128); W1/W2 staged via global_load_lds w16 with pre-swizzled source.
__device__ __forceinline__ void stage_w1(const unsigned short* w1e, short* W1s,
                                         int hcn, int wid, int lane) {
    #pragma unroll
    for (int k2 = 0; k2 < 2; ++k2) {
        int i2 = wid * 2 + k2;
        int r2 = i2 * 4 + (lane >> 4);          // hid-local row 0..63
        int s2 = lane & 15;                      // 16B slot 0..15
        gll16(w1e + (size_t)(hcn + r2) * 128 + ((s2 ^ (r2 & 15)) * 8),
              W1s + i2 * 512);
    }
}
__device__ __forceinline__ void stage_w2(const unsigned short* w2e, short* W2s,
                                         int hcn, int wid, int lane) {
    #pragma unroll
    for (int k2 = 0; k2 < 2; ++k2) {
        int i2 = wid * 2 + k2;
        int r2 = i2 * 8 + (lane >> 3);          // d row 0..127
        int s2 = lane & 7;                       // 16B slot 0..7
        gll16(w2e + (size_t)r2 * 512 + hcn + ((s2 ^ (r2 & 7)) * 8),
              W2s + i2 * 512);
    }
}

__global__ __launch_bounds__(512, 4) void moe_mfma_kernel(
    const unsigned short* __restrict__ xtb,
    const int* __restrict__ pair_tok, const int* __restrict__ blk2e,
    const int* __restrict__ blk2chunk, const int* __restrict__ poff,
    const int* __restrict__ total_chunks,
    const unsigned short* __restrict__ w1bt,   // [E][HID][D] bf16
    const float* __restrict__ b1,
    const unsigned short* __restrict__ w2bt,   // [E][D][HID] bf16
    const float* __restrict__ b2,
    unsigned short* __restrict__ pair_y)       // [Ppad][128] bf16
{
    __shared__ short Xs[128 * 128];    // [tok][d]   swz mask 15 (256B rows)
    __shared__ short Hs[128 * 64];     // [tok][hid] swz mask 7  (128B rows)
    __shared__ short W1s[64 * 128];    // [hid][d]   swz mask 15
    __shared__ short W2s[128 * 64];    // [d][hid]   swz mask 7

    const int blk = blockIdx.x;
    if (blk >= *total_chunks) return;
    const int e  = blk2e[blk];
    const int p0 = poff[e] + (blk2chunk[blk] << 7);
    const int tid  = threadIdx.x;
    const int lane = tid & 63;
    const int wid  = tid >> 6;       // 0..7
    const int wm   = wid >> 1;       // 0..3 -> token rows wm*32
    const int wn   = wid & 1;        // 0..1
    const int l16  = lane & 15;
    const int lg   = lane >> 4;      // 0..3

    const unsigned short* w1e = w1bt + (size_t)e * 512 * 128;
    const unsigned short* w2e = w2bt + (size_t)e * 128 * 512;

    // issue chunk-0 weight staging (async)
    stage_w1(w1e, W1s, 0, wid, lane);
    stage_w2(w2e, W2s, 0, wid, lane);

    // stage X tile via registers (gather rows, zero-pad), swizzled stores
    #pragma unroll
    for (int i = 0; i < 4; ++i) {
        int lin = i * 512 + tid;              // 0..2047
        int row = lin >> 4, kc = lin & 15;
        int tok = pair_tok[p0 + row];
        short8v v = {};
        if (tok >= 0)
            v = *(const short8v*)(xtb + (size_t)tok * 128 + kc * 8);
        *(short8v*)(Xs + row * 128 + ((kc ^ (row & 15)) * 8)) = v;
    }

    f32x4 yacc[2][4];
    #pragma unroll
    for (int mi = 0; mi < 2; ++mi)
        #pragma unroll
        for (int ni = 0; ni < 4; ++ni)
            yacc[mi][ni] = (f32x4){0.f, 0.f, 0.f, 0.f};

    const int rowA0 = wm * 32 + l16, rowA1 = rowA0 + 16;

    for (int c = 0; c < 8; ++c) {
        WAIT_VMLGKM(); SBAR();                 // W(c) landed; Hs free; Xs visible

        // ---- layer 1: H_chunk[128 tok][64 hid] = relu(X @ W1 + b1) ----
        f32x4 hacc[2][2];
        #pragma unroll
        for (int mi = 0; mi < 2; ++mi)
            #pragma unroll
            for (int ni = 0; ni < 2; ++ni)
                hacc[mi][ni] = (f32x4){0.f, 0.f, 0.f, 0.f};

        #pragma unroll
        for (int kk = 0; kk < 4; ++kk) {
            int slot = kk * 4 + lg;
            short8v a0 = *(const short8v*)(Xs + rowA0 * 128 + ((slot ^ (rowA0 & 15)) * 8));
            short8v a1 = *(const short8v*)(Xs + rowA1 * 128 + ((slot ^ (rowA1 & 15)) * 8));
            #pragma unroll
            for (int ni = 0; ni < 2; ++ni) {
                int hr = wn * 32 + ni * 16 + l16;
                short8v bfr = *(const short8v*)(W1s + hr * 128 + ((slot ^ (hr & 15)) * 8));
                hacc[0][ni] = __builtin_amdgcn_mfma_f32_16x16x32_bf16(a0, bfr, hacc[0][ni], 0, 0, 0);
                hacc[1][ni] = __builtin_amdgcn_mfma_f32_16x16x32_bf16(a1, bfr, hacc[1][ni], 0, 0, 0);
            }
        }
        // relu + b1 -> Hs (swizzled b16 writes). D frag: col=lane&15, row=(lane>>4)*4+r
        #pragma unroll
        for (int ni = 0; ni < 2; ++ni) {
            int col = wn * 32 + ni * 16 + l16;
            float b1v = b1[e * 512 + (c << 6) + col];
            #pragma unroll
            for (int mi = 0; mi < 2; ++mi) {
                #pragma unroll
                for (int r = 0; r < 4; ++r) {
                    int m = wm * 32 + mi * 16 + lg * 4 + r;
                    float v = fmaxf(hacc[mi][ni][r] + b1v, 0.f);
                    Hs[m * 64 + (((col >> 3) ^ (m & 7)) << 3) + (col & 7)] = (short)f2bf(v);
                }
            }
        }
        WAIT_LGKM(); SBAR();                   // Hs visible; W1s free

        if (c < 7) stage_w1(w1e, W1s, (c + 1) << 6, wid, lane);  // overlaps layer 2

        // ---- layer 2: Y += H_chunk @ W2[hc:hc+64, :] ----
        #pragma unroll
        for (int kk = 0; kk < 2; ++kk) {
            int slot = kk * 4 + lg;
            short8v a0 = *(const short8v*)(Hs + rowA0 * 64 + ((slot ^ (rowA0 & 7)) * 8));
            short8v a1 = *(const short8v*)(Hs + rowA1 * 64 + ((slot ^ (rowA1 & 7)) * 8));
            #pragma unroll
            for (int ni = 0; ni < 4; ++ni) {
                int dr = wn * 64 + ni * 16 + l16;
                short8v bfr = *(const short8v*)(W2s + dr * 64 + ((slot ^ (dr & 7)) * 8));
                yacc[0][ni] = __builtin_amdgcn_mfma_f32_16x16x32_bf16(a0, bfr, yacc[0][ni], 0, 0, 0);
                yacc[1][ni] = __builtin_amdgcn_mfma_f32_16x16x32_bf16(a1, bfr, yacc[1][ni], 0, 0, 0);
            }
        }
        // RACE FIX (R6->R7): drain this wave's layer-2 ds_reads BEFORE the
        // barrier. Without it, a wave whose MFMAs (+compiler waitcnt) were
        // scheduled below the barrier crosses with W2s reads outstanding,
        // while the first wave past the barrier issues stage_w2(c+1) whose
        // DMA can overwrite W2s -> intermittent corruption (R6 replay fail).
        WAIT_LGKM(); SBAR();                   // W2s reads retired

        if (c < 7) stage_w2(w2e, W2s, (c + 1) << 6, wid, lane);
    }

    // epilogue: pair_y = bf16(Y + b2)
    #pragma unroll
    for (int ni = 0; ni < 4; ++ni) {
        int d = wn * 64 + ni * 16 + l16;
        float b2v = b2[e * 128 + d];
        #pragma unroll
        for (int mi = 0; mi < 2; ++mi) {
            #pragma unroll
            for (int r = 0; r < 4; ++r) {
                int m = wm * 32 + mi * 16 + lg * 4 + r;
                pair_y[(size_t)(p0 + m) * 128 + d] = f2bf(yacc[mi][ni][r] + b2v);
            }
        }
    }
}

// ---------------- combine: out[t] = p0*y0 + p1*y1 (NCHW store) ----------------
__global__ __launch_bounds__(256) void combine_kernel(
    const unsigned short* __restrict__ pair_y, const int* __restrict__ slot_of,
    const float* __restrict__ top_prob, float* __restrict__ out)
{
    __shared__ float ob[64][129];
    const int blk = blockIdx.x;               // 512
    const int b = blk >> 4;
    const int hw0 = (blk & 15) << 6;
    const int tid = threadIdx.x;
    #pragma unroll
    for (int i = 0; i < 4; ++i) {
        int lin = i * 256 + tid;              // 0..1023
        int tl = lin >> 4, dg = lin & 15;
        int t = b * 1024 + hw0 + tl;
        int s0 = slot_of[t * 2], s1 = slot_of[t * 2 + 1];
        float p0 = top_prob[t * 2], p1 = top_prob[t * 2 + 1];
        short8v y0 = *(const short8v*)(pair_y + (size_t)s0 * 128 + dg * 8);
        short8v y1 = *(const short8v*)(pair_y + (size_t)s1 * 128 + dg * 8);
        #pragma unroll
        for (int j = 0; j < 8; ++j)
            ob[tl][dg * 8 + j] = p0 * bf2f((unsigned short)y0[j]) + p1 * bf2f((unsigned short)y1[j]);
    }
    __syncthreads();
    #pragma unroll
    for (int i = 0; i < 32; ++i) {
        int lin = i * 256 + tid;
        int d = lin >> 6, hwl = lin & 63;
        out[((size_t)b * 128 + d) * 1024 + hw0 + hwl] = ob[hwl][d];
    }
}

// ---------------- fallback per-token expert kernel ----------------------------
__global__ __launch_bounds__(256) void moe_expert_kernel(
    const float* __restrict__ x,
    const int* __restrict__ top_idx, const float* __restrict__ top_prob,
    const float* __restrict__ w1, const float* __restrict__ b1,
    const float* __restrict__ w2, const float* __restrict__ b2,
    float* __restrict__ out)
{
    __shared__ float xsB[128];
    __shared__ float hb[512];

    const int tid = threadIdx.x;
    const int t = blockIdx.x;
    const int b = t >> 10, hw = t & 1023;

    if (tid < 128)
        xsB[tid] = x[((size_t)b * 128 + tid) * NHW + hw];
    __syncthreads();

    float oacc = 0.f;
    #pragma unroll
    for (int k = 0; k < 2; ++k) {
        const int e = top_idx[t * 2 + k];
        const float pw = top_prob[t * 2 + k];
        const float* W1 = w1 + (size_t)e * (128 * 512);
        float a0 = 0.f, a1 = 0.f;
        for (int d = 0; d < 128; ++d) {
            float xv = xsB[d];
            a0 = fmaf(xv, W1[d * 512 + tid], a0);
            a1 = fmaf(xv, W1[d * 512 + tid + 256], a1);
        }
        hb[tid]       = fmaxf(a0 + b1[e * 512 + tid], 0.f);
        hb[tid + 256] = fmaxf(a1 + b1[e * 512 + tid + 256], 0.f);
        __syncthreads();
        if (tid < 128) {
            const float* W2 = w2 + (size_t)e * (512 * 128);
            float a = 0.f;
            for (int h = 0; h < 512; ++h)
                a = fmaf(hb[h], W2[h * 128 + tid], a);
            oacc = fmaf(pw, a + b2[e * 128 + tid], oacc);
        }
        __syncthreads();
    }
    if (tid < 128)
        out[((size_t)b * 128 + tid) * NHW + hw] = oacc;
}

// ---------------- host launch -------------------------------------------------
extern "C" void kernel_launch(void* const* d_in, const int* in_sizes, int n_in,
                              void* d_out, int out_size, void* d_ws, size_t ws_size,
                              hipStream_t stream) {
    const float* x       = (const float*)d_in[0];
    const float* gate_w  = (const float*)d_in[1];
    const float* gate_b  = (const float*)d_in[2];
    const float* noise_w = (const float*)d_in[3];
    const float* noise_b = (const float*)d_in[4];
    const float* w1      = (const float*)d_in[5];
    const float* b1      = (const float*)d_in[6];
    const float* w2      = (const float*)d_in[7];
    const float* b2      = (const float*)d_in[8];

    float* out   = (float*)d_out;                   // [32,128,32,32]
    float* gates = out + (size_t)NB * NC * NHW;     // [T,16]

    // workspace layout (byte offsets)
    const size_t OFF_CNT    = 0;          // 16 ints
    const size_t OFF_POFF   = 1024;       // 16 ints
    const size_t OFF_TOTAL  = 2048;       // 1 int
    const size_t OFF_B2E    = 4096;       // 544 ints
    const size_t OFF_B2C    = 8192;       // 544 ints
    const size_t OFF_TIDX   = 12288;      // T*2 ints
    const size_t OFF_RANK   = OFF_TIDX + (size_t)NT * 2 * 4;
    const size_t OFF_SLOT   = OFF_RANK + (size_t)NT * 2 * 4;
    const size_t OFF_PROB   = OFF_SLOT + (size_t)NT * 2 * 4;
    const size_t OFF_XTB    = OFF_PROB + (size_t)NT * 2 * 4;
    const size_t OFF_W1BT   = OFF_XTB + (size_t)NT * 128 * 2;
    const size_t OFF_W2BT   = OFF_W1BT + (size_t)NE * 512 * 128 * 2;
    const size_t OFF_PTOK   = OFF_W2BT + (size_t)NE * 128 * 512 * 2;
    const size_t NPAIR_PAD  = 67584;
    const size_t OFF_PAIRY  = OFF_PTOK + NPAIR_PAD * 4;
    const size_t NEED       = OFF_PAIRY + NPAIR_PAD * 128 * 2;   // pair_y bf16

    char* ws = (char*)d_ws;
    int*   cnt      = (int*)(ws + OFF_CNT);
    int*   poff     = (int*)(ws + OFF_POFF);
    int*   total_ch = (int*)(ws + OFF_TOTAL);
    int*   blk2e    = (int*)(ws + OFF_B2E);
    int*   blk2c    = (int*)(ws + OFF_B2C);
    int*   top_idx  = (int*)(ws + OFF_TIDX);
    int*   rank     = (int*)(ws + OFF_RANK);
    int*   slot_of  = (int*)(ws + OFF_SLOT);
    float* top_prob = (float*)(ws + OFF_PROB);
    unsigned short* xtb    = (unsigned short*)(ws + OFF_XTB);
    unsigned short* w1bt   = (unsigned short*)(ws + OFF_W1BT);
    unsigned short* w2bt   = (unsigned short*)(ws + OFF_W2BT);
    int*   pair_tok = (int*)(ws + OFF_PTOK);
    unsigned short* pair_y = (unsigned short*)(ws + OFF_PAIRY);

    const int use_new = (ws_size >= NEED) ? 1 : 0;

    if (use_new)
        hipMemsetAsync(cnt, 0, 16 * sizeof(int), stream);

    moe_gate_kernel<<<NT / 64, 256, 0, stream>>>(
        x, gate_w, gate_b, noise_w, noise_b,
        gates, top_idx, top_prob, rank, cnt, xtb, use_new);

    if (use_new) {
        // w1[e][128][512] -> w1bt[e][512][128] ; w2[e][512][128] -> w2bt[e][128][512]
        transpose_convert_kernel<<<NE * 2 * 8, 256, 0, stream>>>(w1, w1bt, 128, 512);
        transpose_convert_kernel<<<NE * 8 * 2, 256, 0, stream>>>(w2, w2bt, 512, 128);
        scan_kernel<<<1, 256, 0, stream>>>(cnt, poff, blk2e, blk2c, total_ch, pair_tok);
        scatter_kernel<<<NT * 2 / 256, 256, 0, stream>>>(top_idx, rank, poff, pair_tok, slot_of);
        moe_mfma_kernel<<<528, 512, 0, stream>>>(
            xtb, pair_tok, blk2e, blk2c, poff, total_ch,
            w1bt, b1, w2bt, b2, pair_y);
        combine_kernel<<<512, 256, 0, stream>>>(pair_y, slot_of, top_prob, out);
    } else {
        moe_expert_kernel<<<NT, 256, 0, stream>>>(
            x, top_idx, top_prob, w1, b1, w2, b2, out);
    }
}

// Round 8
// 95.643 us; speedup vs baseline: 3.2667x; 1.0109x over previous
//
#include <hip/hip_runtime.h>
#include <stdint.h>

// Problem constants (fixed by the reference)
#define NB       32
#define NC       128
#define NHW      1024            // H*W
#define NT       32768           // tokens
#define NE       16
#define NHID     512
#define NGBLK    512             // gate blocks (64 tokens each)

typedef __attribute__((ext_vector_type(8))) short short8v;   // 8 x bf16 (4 VGPRs)
typedef __attribute__((ext_vector_type(4))) float f32x4;

__device__ __forceinline__ unsigned short f2bf(float f) {
    uint32_t u = __float_as_uint(f);
    uint32_t r = u + 0x7fffu + ((u >> 16) & 1u);   // RNE (finite values)
    return (unsigned short)(r >> 16);
}
__device__ __forceinline__ float bf2f(unsigned short u) {
    return __uint_as_float(((uint32_t)u) << 16);
}

// async global->LDS, 16B per lane; LDS dest = base + lane*16 (linear),
// so swizzling is done on the per-lane GLOBAL source address (m173 pattern).
__device__ __forceinline__ void gll16(const void* g, void* l) {
    __builtin_amdgcn_global_load_lds(
        (const __attribute__((address_space(1))) uint32_t*)g,
        (__attribute__((address_space(3))) uint32_t*)l, 16, 0, 0);
}

#define WAIT_VMLGKM() asm volatile("s_waitcnt vmcnt(0) lgkmcnt(0)" ::: "memory")
#define WAIT_LGKM()   asm volatile("s_waitcnt lgkmcnt(0)" ::: "memory")
#define SBAR()        { asm volatile("" ::: "memory"); __builtin_amdgcn_s_barrier(); asm volatile("" ::: "memory"); }

// ---------------- Threefry-2x32, 20 rounds (JAX) ----------------
__device__ __forceinline__ uint32_t rotl32(uint32_t x, uint32_t d) {
    return (x << d) | (x >> (32u - d));
}

__device__ __forceinline__ void threefry2x32_20(uint32_t k0, uint32_t k1,
                                                uint32_t& x0, uint32_t& x1) {
    const uint32_t ks0 = k0, ks1 = k1, ks2 = k0 ^ k1 ^ 0x1BD11BDAu;
    x0 += ks0; x1 += ks1;
#define TFR(r) { x0 += x1; x1 = rotl32(x1, r); x1 ^= x0; }
    TFR(13u) TFR(15u) TFR(26u) TFR(6u)
    x0 += ks1; x1 += ks2 + 1u;
    TFR(17u) TFR(29u) TFR(16u) TFR(24u)
    x0 += ks2; x1 += ks0 + 2u;
    TFR(13u) TFR(15u) TFR(26u) TFR(6u)
    x0 += ks0; x1 += ks1 + 3u;
    TFR(17u) TFR(29u) TFR(16u) TFR(24u)
    x0 += ks1; x1 += ks2 + 4u;
    TFR(13u) TFR(15u) TFR(26u) TFR(6u)
    x0 += ks2; x1 += ks0 + 5u;
#undef TFR
}

__device__ __forceinline__ float erfinv_xla_f32(float x) {
    float w = -log1pf(-x * x);
    float p;
    if (w < 5.0f) {
        w = w - 2.5f;
        p = 2.81022636e-08f;
        p = fmaf(p, w, 3.43273939e-07f);
        p = fmaf(p, w, -3.5233877e-06f);
        p = fmaf(p, w, -4.39150654e-06f);
        p = fmaf(p, w, 0.00021858087f);
        p = fmaf(p, w, -0.00125372503f);
        p = fmaf(p, w, -0.00417768164f);
        p = fmaf(p, w, 0.246640727f);
        p = fmaf(p, w, 1.50140941f);
    } else {
        w = sqrtf(w) - 3.0f;
        p = -0.000200214257f;
        p = fmaf(p, w, 0.000100950558f);
        p = fmaf(p, w, 0.00134934322f);
        p = fmaf(p, w, -0.00367342844f);
        p = fmaf(p, w, 0.00573950773f);
        p = fmaf(p, w, -0.0076224613f);
        p = fmaf(p, w, 0.00943887047f);
        p = fmaf(p, w, 1.00167406f);
        p = fmaf(p, w, 2.83297682f);
    }
    return p * x;
}

__device__ __forceinline__ float jax_noise_elem(uint32_t i) {
    uint32_t x0 = 0u, x1 = i;
    threefry2x32_20(0u, 42u, x0, x1);
    uint32_t bits = x0 ^ x1;
    float f = __uint_as_float(0x3f800000u | (bits >> 9)) - 1.0f;
    const float lo = -0.99999994f;
    float u = f * 2.0f + lo;
    u = fmaxf(lo, u);
    return 1.41421354f * erfinv_xla_f32(u);
}

// ---------------- Kernel A: gating + noise + top-2 (+ xtb emit) ---------------
// 4 threads per token, 64 tokens/block. NO global atomics: per-block histogram
// bcnt[blk][16] (plain stores) + per-token LOCAL rank; bases come from scan.
__global__ __launch_bounds__(256) void moe_gate_kernel(
    const float* __restrict__ x,
    const float* __restrict__ gate_w, const float* __restrict__ gate_b,
    const float* __restrict__ noise_w, const float* __restrict__ noise_b,
    float* __restrict__ gates_out,        // [T,16] region of d_out
    int*   __restrict__ top_idx,          // [T,2]
    float* __restrict__ top_prob,         // [T,2]
    int*   __restrict__ rank,             // [T,2] local ranks
    int*   __restrict__ bcnt,             // [512][16]
    unsigned short* __restrict__ xtb,     // [T,128] bf16
    int do_new)
{
    __shared__ float lw[32 * 160];        // [ci=32][q=4][40]; e<16 gate, e>=16 noise
    __shared__ int   lcnt[16];

    const int tid = threadIdx.x;
    const int tl  = tid >> 2;                     // token within block (0..63)
    const int q   = tid & 3;                      // channel quarter
    const int t   = blockIdx.x * 64 + tl;         // global token
    const int b   = t >> 10, hw = t & 1023;

    if (tid < 16) lcnt[tid] = 0;

    for (int idx = tid; idx < 4096; idx += 256) {
        int ci = idx >> 7;
        int r  = idx & 127;
        int qq = r >> 5, e = r & 31;
        int c  = qq * 32 + ci;
        float v = (e < 16) ? gate_w[c * 16 + e] : noise_w[c * 16 + (e - 16)];
        lw[ci * 160 + qq * 40 + e] = v;
    }
    __syncthreads();

    float acc[32];
    #pragma unroll
    for (int e = 0; e < 32; ++e) acc[e] = 0.f;

    unsigned short xh[32];
    const float* xq = x + (size_t)b * (NC * NHW) + (size_t)(q * 32) * NHW + hw;
    const float* wq = lw + q * 40;
    #pragma unroll 4
    for (int ci = 0; ci < 32; ++ci) {
        float xv = xq[(size_t)ci << 10];
        xh[ci] = f2bf(xv);
        const f32x4* wr = (const f32x4*)(wq + ci * 160);
        #pragma unroll
        for (int j = 0; j < 8; ++j) {
            f32x4 w4 = wr[j];
            #pragma unroll
            for (int k = 0; k < 4; ++k)
                acc[j * 4 + k] = fmaf(xv, w4[k], acc[j * 4 + k]);
        }
    }

    if (do_new) {
        #pragma unroll
        for (int j = 0; j < 4; ++j) {
            short8v v;
            #pragma unroll
            for (int k = 0; k < 8; ++k) v[k] = (short)xh[j * 8 + k];
            *(short8v*)(xtb + (size_t)t * 128 + q * 32 + j * 8) = v;
        }
    }

    #pragma unroll
    for (int e = 0; e < 32; ++e) {
        acc[e] += __shfl_xor(acc[e], 1);
        acc[e] += __shfl_xor(acc[e], 2);
    }

    float lg[4];
    #pragma unroll
    for (int j = 0; j < 4; ++j) {
        int e = q * 4 + j;
        float g  = acc[e] + gate_b[e];
        float an = acc[16 + e] + noise_b[e];
        float sd = fmaxf(an, 0.f) + log1pf(expf(-fabsf(an)));
        float nz = jax_noise_elem((uint32_t)t * 16u + (uint32_t)e);
        lg[j] = fmaf(nz, sd, g);
    }

    // local top-2 (value desc, index asc — matches lax.top_k stability)
    float v1 = lg[0], v2 = -INFINITY;
    int   i1 = q * 4, i2 = 0x7fffffff;
    #pragma unroll
    for (int j = 1; j < 4; ++j) {
        float v = lg[j]; int e = q * 4 + j;
        if (v > v1) { v2 = v1; i2 = i1; v1 = v; i1 = e; }
        else if (v > v2) { v2 = v; i2 = e; }
    }
    #pragma unroll
    for (int m = 1; m <= 2; m <<= 1) {
        float pv1 = __shfl_xor(v1, m), pv2 = __shfl_xor(v2, m);
        int   pi1 = __shfl_xor(i1, m), pi2 = __shfl_xor(i2, m);
        bool pBest = (pv1 > v1) || (pv1 == v1 && pi1 < i1);
        float c2v; int c2i;
        if (pBest) { c2v = v1;  c2i = i1;  v1 = pv1; i1 = pi1;
                     if (!((c2v > pv2) || (c2v == pv2 && c2i < pi2))) { c2v = pv2; c2i = pi2; }
        } else     { c2v = pv1; c2i = pi1;
                     if (!((c2v > v2)  || (c2v == v2  && c2i < i2)))  { c2v = v2;  c2i = i2;  }
        }
        v2 = c2v; i2 = c2i;
    }

    float qq = expf(v2 - v1);
    float s  = 1.0f + qq;
    float p1 = 1.0f / s;
    float p2 = qq / s;

    f32x4 g4;
    #pragma unroll
    for (int j = 0; j < 4; ++j) {
        int e = q * 4 + j;
        g4[j] = (e == i1) ? p1 : ((e == i2) ? p2 : 0.f);
    }
    *(f32x4*)(gates_out + (size_t)t * 16 + q * 4) = g4;

    if (q == 0) {
        top_idx[t * 2 + 0] = i1;  top_idx[t * 2 + 1] = i2;
        top_prob[t * 2 + 0] = p1; top_prob[t * 2 + 1] = p2;
        if (do_new) {
            int r1 = atomicAdd(&lcnt[i1], 1);   // LDS atomics only
            int r2 = atomicAdd(&lcnt[i2], 1);
            rank[t * 2 + 0] = r1;
            rank[t * 2 + 1] = r2;
        }
    }
    if (do_new) {
        __syncthreads();                         // lcnt final
        if (tid < 16) bcnt[blockIdx.x * 16 + tid] = lcnt[tid];
    }
}

// ---- fused weight transpose+convert: blk<256 -> w1, else w2 ------------------
// w1[e][128][512] -> w1bt[e][512][128] ; w2[e][512][128] -> w2bt[e][128][512]
__global__ __launch_bounds__(256) void transpose_convert2_kernel(
    const float* __restrict__ w1, unsigned short* __restrict__ w1bt,
    const float* __restrict__ w2, unsigned short* __restrict__ w2bt)
{
    __shared__ float ts[64][65];
    int blk = blockIdx.x;
    const float* src;  unsigned short* dst;  int R, C;
    if (blk < 256) { src = w1; dst = w1bt; R = 128; C = 512; }
    else           { src = w2; dst = w2bt; R = 512; C = 128; blk -= 256; }
    const int nr = R >> 6, ncc = C >> 6;
    const int e = blk / (nr * ncc);
    const int rem = blk % (nr * ncc);
    const int rt = rem / ncc, ct = rem % ncc;
    const float* S = src + (size_t)e * R * C + (size_t)(rt * 64) * C + ct * 64;
    unsigned short* D = dst + (size_t)e * R * C + (size_t)(ct * 64) * R + rt * 64;
    const int tid = threadIdx.x;
    #pragma unroll
    for (int i = 0; i < 16; ++i) {
        int lin = i * 256 + tid;
        int r = lin >> 6, c = lin & 63;
        ts[r][c] = S[(size_t)r * C + c];
    }
    __syncthreads();
    #pragma unroll
    for (int i = 0; i < 16; ++i) {
        int lin = i * 256 + tid;
        int c = lin >> 6, r = lin & 63;
        D[(size_t)c * R + r] = f2bf(ts[r][c]);
    }
}

// ---- scan: hierarchical prefix over bcnt[512][16] -> poff, bbase, tables -----
__global__ __launch_bounds__(256) void scan_kernel(
    const int* __restrict__ bcnt,        // [512][16]
    int* __restrict__ poff, int* __restrict__ blk2e,
    int* __restrict__ blk2chunk, int* __restrict__ total_chunks,
    int* __restrict__ bbase,             // [512][16]
    int* __restrict__ pair_tok)
{
    __shared__ int ps[16][17];           // [e][g] group partial sums
    __shared__ int gb[16][17];           // [e][g] group exclusive prefix
    __shared__ int scnt[16];
    __shared__ int snch[16];
    __shared__ int scum[17];
    __shared__ int spoff[16];
    const int tid = threadIdx.x;         // 256
    const int e = tid >> 4, g = tid & 15;

    // Phase A: partial sums over this group's 32 gate-blocks
    int s = 0;
    for (int b = g * 32; b < g * 32 + 32; ++b)
        s += bcnt[b * 16 + e];
    ps[e][g] = s;
    __syncthreads();

    // Phase B: per-expert scan of the 16 group sums
    if (tid < 16) {
        int run = 0;
        for (int gg = 0; gg < 16; ++gg) { gb[tid][gg] = run; run += ps[tid][gg]; }
        scnt[tid] = run;
        snch[tid] = (run + 127) >> 7;
    }
    __syncthreads();

    // Phase C: expert-level padded offsets + chunk tables
    if (tid == 0) {
        int cc = 0, off = 0;
        for (int ee = 0; ee < 16; ++ee) {
            scum[ee] = cc; spoff[ee] = off;
            cc += snch[ee]; off += snch[ee] << 7;
        }
        scum[16] = cc;
        *total_chunks = cc;
    }
    __syncthreads();
    const int tot = scum[16];
    for (int idx = tid; idx < tot; idx += 256) {
        int ee = 0;
        #pragma unroll
        for (int k = 0; k < 15; ++k)
            if (idx >= scum[k + 1]) ee = k + 1;
        blk2e[idx] = ee;
        blk2chunk[idx] = idx - scum[ee];
    }
    if (tid < 16) poff[tid] = spoff[tid];

    // Phase D: per-(gate-block, expert) base
    {
        int run = spoff[e] + gb[e][g];
        for (int b = g * 32; b < g * 32 + 32; ++b) {
            bbase[b * 16 + e] = run;
            run += bcnt[b * 16 + e];
        }
    }

    // Phase E: pad fill
    for (int ee = 0; ee < 16; ++ee) {
        int start = spoff[ee] + scnt[ee];
        int end   = spoff[ee] + (snch[ee] << 7);
        for (int i = start + tid; i < end; i += 256)
            pair_tok[i] = -1;
    }
}

// ---------------- scatter pairs into expert bins ------------------------------
__global__ __launch_bounds__(256) void scatter_kernel(
    const int* __restrict__ top_idx, const int* __restrict__ rank,
    const int* __restrict__ bbase, int* __restrict__ pair_tok,
    int* __restrict__ slot_of)
{
    int i = blockIdx.x * 256 + threadIdx.x;   // 0..65535
    int t = i >> 1;
    int e = top_idx[i];
    int slot = bbase[(t >> 6) * 16 + e] + rank[i];
    pair_tok[slot] = t;
    slot_of[i] = slot;
}

// ---------------- grouped MFMA MLP: 1 block = (expert, 128 pairs) -------------
// LDS = exactly 80 KB -> 2 blocks/CU. XOR-swizzled tiles (conflict-free
// ds_read_b128); W1/W2 staged via global_load_lds w16 with pre-swizzled source.
__device__ __forceinline__ void stage_w1(const unsigned short* w1e, short* W1s,
                                         int hcn, int wid, int lane) {
    #pragma unroll
    for (int k2 = 0; k2 < 2; ++k2) {
        int i2 = wid * 2 + k2;
        int r2 = i2 * 4 + (lane >> 4);          // hid-local row 0..63
        int s2 = lane & 15;                      // 16B slot 0..15
        gll16(w1e + (size_t)(hcn + r2) * 128 + ((s2 ^ (r2 & 15)) * 8),
              W1s + i2 * 512);
    }
}
__device__ __forceinline__ void stage_w2(const unsigned short* w2e, short* W2s,
                                         int hcn, int wid, int lane) {
    #pragma unroll
    for (int k2 = 0; k2 < 2; ++k2) {
        int i2 = wid * 2 + k2;
        int r2 = i2 * 8 + (lane >> 3);          // d row 0..127
        int s2 = lane & 7;                       // 16B slot 0..7
        gll16(w2e + (size_t)r2 * 512 + hcn + ((s2 ^ (r2 & 7)) * 8),
              W2s + i2 * 512);
    }
}

__global__ __launch_bounds__(512, 4) void moe_mfma_kernel(
    const unsigned short* __restrict__ xtb,
    const int* __restrict__ pair_tok, const int* __restrict__ blk2e,
    const int* __restrict__ blk2chunk, const int* __restrict__ poff,
    const int* __restrict__ total_chunks,
    const unsigned short* __restrict__ w1bt,   // [E][HID][D] bf16
    const float* __restrict__ b1,
    const unsigned short* __restrict__ w2bt,   // [E][D][HID] bf16
    const float* __restrict__ b2,
    unsigned short* __restrict__ pair_y)       // [Ppad][128] bf16
{
    __shared__ short Xs[128 * 128];    // [tok][d]   swz mask 15 (256B rows)
    __shared__ short Hs[128 * 64];     // [tok][hid] swz mask 7  (128B rows)
    __shared__ short W1s[64 * 128];    // [hid][d]   swz mask 15
    __shared__ short W2s[128 * 64];    // [d][hid]   swz mask 7

    const int blk = blockIdx.x;
    if (blk >= *total_chunks) return;
    const int e  = blk2e[blk];
    const int p0 = poff[e] + (blk2chunk[blk] << 7);
    const int tid  = threadIdx.x;
    const int lane = tid & 63;
    const int wid  = tid >> 6;       // 0..7
    const int wm   = wid >> 1;       // 0..3 -> token rows wm*32
    const int wn   = wid & 1;        // 0..1
    const int l16  = lane & 15;
    const int lg   = lane >> 4;      // 0..3

    const unsigned short* w1e = w1bt + (size_t)e * 512 * 128;
    const unsigned short* w2e = w2bt + (size_t)e * 128 * 512;

    // issue chunk-0 weight staging (async)
    stage_w1(w1e, W1s, 0, wid, lane);
    stage_w2(w2e, W2s, 0, wid, lane);

    // stage X tile via registers (gather rows, zero-pad), swizzled stores
    #pragma unroll
    for (int i = 0; i < 4; ++i) {
        int lin = i * 512 + tid;              // 0..2047
        int row = lin >> 4, kc = lin & 15;
        int tok = pair_tok[p0 + row];
        short8v v = {};
        if (tok >= 0)
            v = *(const short8v*)(xtb + (size_t)tok * 128 + kc * 8);
        *(short8v*)(Xs + row * 128 + ((kc ^ (row & 15)) * 8)) = v;
    }

    f32x4 yacc[2][4];
    #pragma unroll
    for (int mi = 0; mi < 2; ++mi)
        #pragma unroll
        for (int ni = 0; ni < 4; ++ni)
            yacc[mi][ni] = (f32x4){0.f, 0.f, 0.f, 0.f};

    const int rowA0 = wm * 32 + l16, rowA1 = rowA0 + 16;

    for (int c = 0; c < 8; ++c) {
        WAIT_VMLGKM(); SBAR();                 // W(c) landed; Hs free; Xs visible

        // ---- layer 1: H_chunk[128 tok][64 hid] = relu(X @ W1 + b1) ----
        f32x4 hacc[2][2];
        #pragma unroll
        for (int mi = 0; mi < 2; ++mi)
            #pragma unroll
            for (int ni = 0; ni < 2; ++ni)
                hacc[mi][ni] = (f32x4){0.f, 0.f, 0.f, 0.f};

        #pragma unroll
        for (int kk = 0; kk < 4; ++kk) {
            int slot = kk * 4 + lg;
            short8v a0 = *(const short8v*)(Xs + rowA0 * 128 + ((slot ^ (rowA0 & 15)) * 8));
            short8v a1 = *(const short8v*)(Xs + rowA1 * 128 + ((slot ^ (rowA1 & 15)) * 8));
            #pragma unroll
            for (int ni = 0; ni < 2; ++ni) {
                int hr = wn * 32 + ni * 16 + l16;
                short8v bfr = *(const short8v*)(W1s + hr * 128 + ((slot ^ (hr & 15)) * 8));
                hacc[0][ni] = __builtin_amdgcn_mfma_f32_16x16x32_bf16(a0, bfr, hacc[0][ni], 0, 0, 0);
                hacc[1][ni] = __builtin_amdgcn_mfma_f32_16x16x32_bf16(a1, bfr, hacc[1][ni], 0, 0, 0);
            }
        }
        // relu + b1 -> Hs (swizzled b16 writes). D frag: col=lane&15, row=(lane>>4)*4+r
        #pragma unroll
        for (int ni = 0; ni < 2; ++ni) {
            int col = wn * 32 + ni * 16 + l16;
            float b1v = b1[e * 512 + (c << 6) + col];
            #pragma unroll
            for (int mi = 0; mi < 2; ++mi) {
                #pragma unroll
                for (int r = 0; r < 4; ++r) {
                    int m = wm * 32 + mi * 16 + lg * 4 + r;
                    float v = fmaxf(hacc[mi][ni][r] + b1v, 0.f);
                    Hs[m * 64 + (((col >> 3) ^ (m & 7)) << 3) + (col & 7)] = (short)f2bf(v);
                }
            }
        }
        WAIT_LGKM(); SBAR();                   // Hs visible; W1s free

        if (c < 7) stage_w1(w1e, W1s, (c + 1) << 6, wid, lane);  // overlaps layer 2

        // ---- layer 2: Y += H_chunk @ W2[hc:hc+64, :] ----
        #pragma unroll
        for (int kk = 0; kk < 2; ++kk) {
            int slot = kk * 4 + lg;
            short8v a0 = *(const short8v*)(Hs + rowA0 * 64 + ((slot ^ (rowA0 & 7)) * 8));
            short8v a1 = *(const short8v*)(Hs + rowA1 * 64 + ((slot ^ (rowA1 & 7)) * 8));
            #pragma unroll
            for (int ni = 0; ni < 4; ++ni) {
                int dr = wn * 64 + ni * 16 + l16;
                short8v bfr = *(const short8v*)(W2s + dr * 64 + ((slot ^ (dr & 7)) * 8));
                yacc[0][ni] = __builtin_amdgcn_mfma_f32_16x16x32_bf16(a0, bfr, yacc[0][ni], 0, 0, 0);
                yacc[1][ni] = __builtin_amdgcn_mfma_f32_16x16x32_bf16(a1, bfr, yacc[1][ni], 0, 0, 0);
            }
        }
        // Drain layer-2 ds_reads BEFORE the barrier (R6 race fix).
        WAIT_LGKM(); SBAR();                   // W2s reads retired

        if (c < 7) stage_w2(w2e, W2s, (c + 1) << 6, wid, lane);
    }

    // epilogue: pair_y = bf16(Y + b2)
    #pragma unroll
    for (int ni = 0; ni < 4; ++ni) {
        int d = wn * 64 + ni * 16 + l16;
        float b2v = b2[e * 128 + d];
        #pragma unroll
        for (int mi = 0; mi < 2; ++mi) {
            #pragma unroll
            for (int r = 0; r < 4; ++r) {
                int m = wm * 32 + mi * 16 + lg * 4 + r;
                pair_y[(size_t)(p0 + m) * 128 + d] = f2bf(yacc[mi][ni][r] + b2v);
            }
        }
    }
}

// ---------------- combine: out[t] = p0*y0 + p1*y1 (NCHW store) ----------------
__global__ __launch_bounds__(256) void combine_kernel(
    const unsigned short* __restrict__ pair_y, const int* __restrict__ slot_of,
    const float* __restrict__ top_prob, float* __restrict__ out)
{
    __shared__ float ob[64][129];
    const int blk = blockIdx.x;               // 512
    const int b = blk >> 4;
    const int hw0 = (blk & 15) << 6;
    const int tid = threadIdx.x;
    #pragma unroll
    for (int i = 0; i < 4; ++i) {
        int lin = i * 256 + tid;              // 0..1023
        int tl = lin >> 4, dg = lin & 15;
        int t = b * 1024 + hw0 + tl;
        int s0 = slot_of[t * 2], s1 = slot_of[t * 2 + 1];
        float p0 = top_prob[t * 2], p1 = top_prob[t * 2 + 1];
        short8v y0 = *(const short8v*)(pair_y + (size_t)s0 * 128 + dg * 8);
        short8v y1 = *(const short8v*)(pair_y + (size_t)s1 * 128 + dg * 8);
        #pragma unroll
        for (int j = 0; j < 8; ++j)
            ob[tl][dg * 8 + j] = p0 * bf2f((unsigned short)y0[j]) + p1 * bf2f((unsigned short)y1[j]);
    }
    __syncthreads();
    #pragma unroll
    for (int i = 0; i < 32; ++i) {
        int lin = i * 256 + tid;
        int d = lin >> 6, hwl = lin & 63;
        out[((size_t)b * 128 + d) * 1024 + hw0 + hwl] = ob[hwl][d];
    }
}

// ---------------- fallback per-token expert kernel ----------------------------
__global__ __launch_bounds__(256) void moe_expert_kernel(
    const float* __restrict__ x,
    const int* __restrict__ top_idx, const float* __restrict__ top_prob,
    const float* __restrict__ w1, const float* __restrict__ b1,
    const float* __restrict__ w2, const float* __restrict__ b2,
    float* __restrict__ out)
{
    __shared__ float xsB[128];
    __shared__ float hb[512];

    const int tid = threadIdx.x;
    const int t = blockIdx.x;
    const int b = t >> 10, hw = t & 1023;

    if (tid < 128)
        xsB[tid] = x[((size_t)b * 128 + tid) * NHW + hw];
    __syncthreads();

    float oacc = 0.f;
    #pragma unroll
    for (int k = 0; k < 2; ++k) {
        const int e = top_idx[t * 2 + k];
        const float pw = top_prob[t * 2 + k];
        const float* W1 = w1 + (size_t)e * (128 * 512);
        float a0 = 0.f, a1 = 0.f;
        for (int d = 0; d < 128; ++d) {
            float xv = xsB[d];
            a0 = fmaf(xv, W1[d * 512 + tid], a0);
            a1 = fmaf(xv, W1[d * 512 + tid + 256], a1);
        }
        hb[tid]       = fmaxf(a0 + b1[e * 512 + tid], 0.f);
        hb[tid + 256] = fmaxf(a1 + b1[e * 512 + tid + 256], 0.f);
        __syncthreads();
        if (tid < 128) {
            const float* W2 = w2 + (size_t)e * (512 * 128);
            float a = 0.f;
            for (int h = 0; h < 512; ++h)
                a = fmaf(hb[h], W2[h * 128 + tid], a);
            oacc = fmaf(pw, a + b2[e * 128 + tid], oacc);
        }
        __syncthreads();
    }
    if (tid < 128)
        out[((size_t)b * 128 + tid) * NHW + hw] = oacc;
}

// ---------------- host launch -------------------------------------------------
extern "C" void kernel_launch(void* const* d_in, const int* in_sizes, int n_in,
                              void* d_out, int out_size, void* d_ws, size_t ws_size,
                              hipStream_t stream) {
    const float* x       = (const float*)d_in[0];
    const float* gate_w  = (const float*)d_in[1];
    const float* gate_b  = (const float*)d_in[2];
    const float* noise_w = (const float*)d_in[3];
    const float* noise_b = (const float*)d_in[4];
    const float* w1      = (const float*)d_in[5];
    const float* b1      = (const float*)d_in[6];
    const float* w2      = (const float*)d_in[7];
    const float* b2      = (const float*)d_in[8];

    float* out   = (float*)d_out;                   // [32,128,32,32]
    float* gates = out + (size_t)NB * NC * NHW;     // [T,16]

    // workspace layout (byte offsets)
    const size_t OFF_POFF   = 0;          // 16 ints
    const size_t OFF_TOTAL  = 1024;       // 1 int
    const size_t OFF_B2E    = 4096;       // 544 ints
    const size_t OFF_B2C    = 8192;       // 544 ints
    const size_t OFF_TIDX   = 12288;      // T*2 ints
    const size_t OFF_RANK   = OFF_TIDX  + (size_t)NT * 2 * 4;
    const size_t OFF_SLOT   = OFF_RANK  + (size_t)NT * 2 * 4;
    const size_t OFF_PROB   = OFF_SLOT  + (size_t)NT * 2 * 4;
    const size_t OFF_BCNT   = OFF_PROB  + (size_t)NT * 2 * 4;     // 512*16 ints
    const size_t OFF_BBASE  = OFF_BCNT  + (size_t)NGBLK * 16 * 4;
    const size_t OFF_XTB    = OFF_BBASE + (size_t)NGBLK * 16 * 4;
    const size_t OFF_W1BT   = OFF_XTB   + (size_t)NT * 128 * 2;
    const size_t OFF_W2BT   = OFF_W1BT  + (size_t)NE * 512 * 128 * 2;
    const size_t OFF_PTOK   = OFF_W2BT  + (size_t)NE * 128 * 512 * 2;
    const size_t NPAIR_PAD  = 67584;
    const size_t OFF_PAIRY  = OFF_PTOK  + NPAIR_PAD * 4;
    const size_t NEED       = OFF_PAIRY + NPAIR_PAD * 128 * 2;   // pair_y bf16

    char* ws = (char*)d_ws;
    int*   poff     = (int*)(ws + OFF_POFF);
    int*   total_ch = (int*)(ws + OFF_TOTAL);
    int*   blk2e    = (int*)(ws + OFF_B2E);
    int*   blk2c    = (int*)(ws + OFF_B2C);
    int*   top_idx  = (int*)(ws + OFF_TIDX);
    int*   rank     = (int*)(ws + OFF_RANK);
    int*   slot_of  = (int*)(ws + OFF_SLOT);
    float* top_prob = (float*)(ws + OFF_PROB);
    int*   bcnt     = (int*)(ws + OFF_BCNT);
    int*   bbase    = (int*)(ws + OFF_BBASE);
    unsigned short* xtb    = (unsigned short*)(ws + OFF_XTB);
    unsigned short* w1bt   = (unsigned short*)(ws + OFF_W1BT);
    unsigned short* w2bt   = (unsigned short*)(ws + OFF_W2BT);
    int*   pair_tok = (int*)(ws + OFF_PTOK);
    unsigned short* pair_y = (unsigned short*)(ws + OFF_PAIRY);

    const int use_new = (ws_size >= NEED) ? 1 : 0;

    moe_gate_kernel<<<NT / 64, 256, 0, stream>>>(
        x, gate_w, gate_b, noise_w, noise_b,
        gates, top_idx, top_prob, rank, bcnt, xtb, use_new);

    if (use_new) {
        transpose_convert2_kernel<<<512, 256, 0, stream>>>(w1, w1bt, w2, w2bt);
        scan_kernel<<<1, 256, 0, stream>>>(bcnt, poff, blk2e, blk2c, total_ch,
                                           bbase, pair_tok);
        scatter_kernel<<<NT * 2 / 256, 256, 0, stream>>>(top_idx, rank, bbase,
                                                         pair_tok, slot_of);
        moe_mfma_kernel<<<528, 512, 0, stream>>>(
            xtb, pair_tok, blk2e, blk2c, poff, total_ch,
            w1bt, b1, w2bt, b2, pair_y);
        combine_kernel<<<512, 256, 0, stream>>>(pair_y, slot_of, top_prob, out);
    } else {
        moe_expert_kernel<<<NT, 256, 0, stream>>>(
            x, top_idx, top_prob, w1, b1, w2, b2, out);
    }
}

// Round 9
// 92.110 us; speedup vs baseline: 3.3920x; 1.0384x over previous
//
#include <hip/hip_runtime.h>
#include <stdint.h>

// Problem constants (fixed by the reference)
#define NB       32
#define NC       128
#define NHW      1024            // H*W
#define NT       32768           // tokens
#define NE       16
#define NHID     512
#define NGBLK    512             // gate blocks (64 tokens each)

typedef __attribute__((ext_vector_type(8))) short short8v;   // 8 x bf16 (4 VGPRs)
typedef __attribute__((ext_vector_type(4))) float f32x4;

__device__ __forceinline__ unsigned short f2bf(float f) {
    uint32_t u = __float_as_uint(f);
    uint32_t r = u + 0x7fffu + ((u >> 16) & 1u);   // RNE (finite values)
    return (unsigned short)(r >> 16);
}
__device__ __forceinline__ float bf2f(unsigned short u) {
    return __uint_as_float(((uint32_t)u) << 16);
}

// async global->LDS, 16B per lane; LDS dest = wave-uniform base + lane*16,
// so swizzling is done on the per-lane GLOBAL source address (m173 pattern).
__device__ __forceinline__ void gll16(const void* g, void* l) {
    __builtin_amdgcn_global_load_lds(
        (const __attribute__((address_space(1))) uint32_t*)g,
        (__attribute__((address_space(3))) uint32_t*)l, 16, 0, 0);
}

#define WAIT_VM2_LGKM0() asm volatile("s_waitcnt vmcnt(2) lgkmcnt(0)" ::: "memory")
#define WAIT_VM2()       asm volatile("s_waitcnt vmcnt(2)" ::: "memory")
#define WAIT_VM0()       asm volatile("s_waitcnt vmcnt(0)" ::: "memory")
#define WAIT_LGKM()      asm volatile("s_waitcnt lgkmcnt(0)" ::: "memory")
#define SBAR()           { asm volatile("" ::: "memory"); __builtin_amdgcn_s_barrier(); asm volatile("" ::: "memory"); }

// ---------------- Threefry-2x32, 20 rounds (JAX) ----------------
__device__ __forceinline__ uint32_t rotl32(uint32_t x, uint32_t d) {
    return (x << d) | (x >> (32u - d));
}

__device__ __forceinline__ void threefry2x32_20(uint32_t k0, uint32_t k1,
                                                uint32_t& x0, uint32_t& x1) {
    const uint32_t ks0 = k0, ks1 = k1, ks2 = k0 ^ k1 ^ 0x1BD11BDAu;
    x0 += ks0; x1 += ks1;
#define TFR(r) { x0 += x1; x1 = rotl32(x1, r); x1 ^= x0; }
    TFR(13u) TFR(15u) TFR(26u) TFR(6u)
    x0 += ks1; x1 += ks2 + 1u;
    TFR(17u) TFR(29u) TFR(16u) TFR(24u)
    x0 += ks2; x1 += ks0 + 2u;
    TFR(13u) TFR(15u) TFR(26u) TFR(6u)
    x0 += ks0; x1 += ks1 + 3u;
    TFR(17u) TFR(29u) TFR(16u) TFR(24u)
    x0 += ks1; x1 += ks2 + 4u;
    TFR(13u) TFR(15u) TFR(26u) TFR(6u)
    x0 += ks2; x1 += ks0 + 5u;
#undef TFR
}

__device__ __forceinline__ float erfinv_xla_f32(float x) {
    float w = -log1pf(-x * x);
    float p;
    if (w < 5.0f) {
        w = w - 2.5f;
        p = 2.81022636e-08f;
        p = fmaf(p, w, 3.43273939e-07f);
        p = fmaf(p, w, -3.5233877e-06f);
        p = fmaf(p, w, -4.39150654e-06f);
        p = fmaf(p, w, 0.00021858087f);
        p = fmaf(p, w, -0.00125372503f);
        p = fmaf(p, w, -0.00417768164f);
        p = fmaf(p, w, 0.246640727f);
        p = fmaf(p, w, 1.50140941f);
    } else {
        w = sqrtf(w) - 3.0f;
        p = -0.000200214257f;
        p = fmaf(p, w, 0.000100950558f);
        p = fmaf(p, w, 0.00134934322f);
        p = fmaf(p, w, -0.00367342844f);
        p = fmaf(p, w, 0.00573950773f);
        p = fmaf(p, w, -0.0076224613f);
        p = fmaf(p, w, 0.00943887047f);
        p = fmaf(p, w, 1.00167406f);
        p = fmaf(p, w, 2.83297682f);
    }
    return p * x;
}

__device__ __forceinline__ float jax_noise_elem(uint32_t i) {
    uint32_t x0 = 0u, x1 = i;
    threefry2x32_20(0u, 42u, x0, x1);
    uint32_t bits = x0 ^ x1;
    float f = __uint_as_float(0x3f800000u | (bits >> 9)) - 1.0f;
    const float lo = -0.99999994f;
    float u = f * 2.0f + lo;
    u = fmaxf(lo, u);
    return 1.41421354f * erfinv_xla_f32(u);
}

// ---------------- Fused kernel A: gate (blk<512) OR weight transpose ----------
// Gate: 4 threads/token, 64 tokens/block, no global atomics (bcnt + local rank).
// Transpose: w1[e][128][512]->w1bt[e][512][128]; w2[e][512][128]->w2bt[e][128][512]
__global__ __launch_bounds__(256) void moe_gate_tw_kernel(
    const float* __restrict__ x,
    const float* __restrict__ gate_w, const float* __restrict__ gate_b,
    const float* __restrict__ noise_w, const float* __restrict__ noise_b,
    float* __restrict__ gates_out,        // [T,16] region of d_out
    int*   __restrict__ top_idx,          // [T,2]
    float* __restrict__ top_prob,         // [T,2]
    int*   __restrict__ rank,             // [T,2] local ranks
    int*   __restrict__ bcnt,             // [512][16]
    unsigned short* __restrict__ xtb,     // [T,128] bf16
    const float* __restrict__ w1, unsigned short* __restrict__ w1bt,
    const float* __restrict__ w2, unsigned short* __restrict__ w2bt,
    int do_new)
{
    __shared__ union { float lw[32 * 160]; float ts[64][65]; } sm;
    __shared__ int lcnt[16];

    const int tid = threadIdx.x;

    if (blockIdx.x >= NGBLK) {
        // ---------------- transpose role ----------------
        int blk = blockIdx.x - NGBLK;
        const float* src;  unsigned short* dst;  int R, C;
        if (blk < 256) { src = w1; dst = w1bt; R = 128; C = 512; }
        else           { src = w2; dst = w2bt; R = 512; C = 128; blk -= 256; }
        const int nr = R >> 6, ncc = C >> 6;
        const int e = blk / (nr * ncc);
        const int rem = blk % (nr * ncc);
        const int rt = rem / ncc, ct = rem % ncc;
        const float* S = src + (size_t)e * R * C + (size_t)(rt * 64) * C + ct * 64;
        unsigned short* D = dst + (size_t)e * R * C + (size_t)(ct * 64) * R + rt * 64;
        #pragma unroll
        for (int i = 0; i < 16; ++i) {
            int lin = i * 256 + tid;
            int r = lin >> 6, c = lin & 63;
            sm.ts[r][c] = S[(size_t)r * C + c];
        }
        __syncthreads();
        #pragma unroll
        for (int i = 0; i < 16; ++i) {
            int lin = i * 256 + tid;
            int c = lin >> 6, r = lin & 63;
            D[(size_t)c * R + r] = f2bf(sm.ts[r][c]);
        }
        return;
    }

    // ---------------- gate role ----------------
    const int tl  = tid >> 2;                     // token within block (0..63)
    const int q   = tid & 3;                      // channel quarter
    const int t   = blockIdx.x * 64 + tl;         // global token
    const int b   = t >> 10, hw = t & 1023;

    if (tid < 16) lcnt[tid] = 0;

    for (int idx = tid; idx < 4096; idx += 256) {
        int ci = idx >> 7;
        int r  = idx & 127;
        int qq = r >> 5, e = r & 31;
        int c  = qq * 32 + ci;
        float v = (e < 16) ? gate_w[c * 16 + e] : noise_w[c * 16 + (e - 16)];
        sm.lw[ci * 160 + qq * 40 + e] = v;
    }
    __syncthreads();

    float acc[32];
    #pragma unroll
    for (int e = 0; e < 32; ++e) acc[e] = 0.f;

    unsigned short xh[32];
    const float* xq = x + (size_t)b * (NC * NHW) + (size_t)(q * 32) * NHW + hw;
    const float* wq = sm.lw + q * 40;
    #pragma unroll 4
    for (int ci = 0; ci < 32; ++ci) {
        float xv = xq[(size_t)ci << 10];
        xh[ci] = f2bf(xv);
        const f32x4* wr = (const f32x4*)(wq + ci * 160);
        #pragma unroll
        for (int j = 0; j < 8; ++j) {
            f32x4 w4 = wr[j];
            #pragma unroll
            for (int k = 0; k < 4; ++k)
                acc[j * 4 + k] = fmaf(xv, w4[k], acc[j * 4 + k]);
        }
    }

    if (do_new) {
        #pragma unroll
        for (int j = 0; j < 4; ++j) {
            short8v v;
            #pragma unroll
            for (int k = 0; k < 8; ++k) v[k] = (short)xh[j * 8 + k];
            *(short8v*)(xtb + (size_t)t * 128 + q * 32 + j * 8) = v;
        }
    }

    #pragma unroll
    for (int e = 0; e < 32; ++e) {
        acc[e] += __shfl_xor(acc[e], 1);
        acc[e] += __shfl_xor(acc[e], 2);
    }

    float lg[4];
    #pragma unroll
    for (int j = 0; j < 4; ++j) {
        int e = q * 4 + j;
        float g  = acc[e] + gate_b[e];
        float an = acc[16 + e] + noise_b[e];
        float sd = fmaxf(an, 0.f) + log1pf(expf(-fabsf(an)));
        float nz = jax_noise_elem((uint32_t)t * 16u + (uint32_t)e);
        lg[j] = fmaf(nz, sd, g);
    }

    // local top-2 (value desc, index asc — matches lax.top_k stability)
    float v1 = lg[0], v2 = -INFINITY;
    int   i1 = q * 4, i2 = 0x7fffffff;
    #pragma unroll
    for (int j = 1; j < 4; ++j) {
        float v = lg[j]; int e = q * 4 + j;
        if (v > v1) { v2 = v1; i2 = i1; v1 = v; i1 = e; }
        else if (v > v2) { v2 = v; i2 = e; }
    }
    #pragma unroll
    for (int m = 1; m <= 2; m <<= 1) {
        float pv1 = __shfl_xor(v1, m), pv2 = __shfl_xor(v2, m);
        int   pi1 = __shfl_xor(i1, m), pi2 = __shfl_xor(i2, m);
        bool pBest = (pv1 > v1) || (pv1 == v1 && pi1 < i1);
        float c2v; int c2i;
        if (pBest) { c2v = v1;  c2i = i1;  v1 = pv1; i1 = pi1;
                     if (!((c2v > pv2) || (c2v == pv2 && c2i < pi2))) { c2v = pv2; c2i = pi2; }
        } else     { c2v = pv1; c2i = pi1;
                     if (!((c2v > v2)  || (c2v == v2  && c2i < i2)))  { c2v = v2;  c2i = i2;  }
        }
        v2 = c2v; i2 = c2i;
    }

    float qq = expf(v2 - v1);
    float s  = 1.0f + qq;
    float p1 = 1.0f / s;
    float p2 = qq / s;

    f32x4 g4;
    #pragma unroll
    for (int j = 0; j < 4; ++j) {
        int e = q * 4 + j;
        g4[j] = (e == i1) ? p1 : ((e == i2) ? p2 : 0.f);
    }
    *(f32x4*)(gates_out + (size_t)t * 16 + q * 4) = g4;

    if (q == 0) {
        top_idx[t * 2 + 0] = i1;  top_idx[t * 2 + 1] = i2;
        top_prob[t * 2 + 0] = p1; top_prob[t * 2 + 1] = p2;
        if (do_new) {
            int r1 = atomicAdd(&lcnt[i1], 1);   // LDS atomics only
            int r2 = atomicAdd(&lcnt[i2], 1);
            rank[t * 2 + 0] = r1;
            rank[t * 2 + 1] = r2;
        }
    }
    if (do_new) {
        __syncthreads();                         // lcnt final
        if (tid < 16) bcnt[blockIdx.x * 16 + tid] = lcnt[tid];
    }
}

// ---- scan: hierarchical prefix over bcnt[512][16] -> poff, bbase, tables -----
__global__ __launch_bounds__(256) void scan_kernel(
    const int* __restrict__ bcnt,        // [512][16]
    int* __restrict__ poff, int* __restrict__ blk2e,
    int* __restrict__ blk2chunk, int* __restrict__ total_chunks,
    int* __restrict__ bbase,             // [512][16]
    int* __restrict__ pair_tok)
{
    __shared__ int ps[16][17];           // [e][g] group partial sums
    __shared__ int gb[16][17];           // [e][g] group exclusive prefix
    __shared__ int scnt[16];
    __shared__ int snch[16];
    __shared__ int scum[17];
    __shared__ int spoff[16];
    const int tid = threadIdx.x;         // 256
    const int e = tid >> 4, g = tid & 15;

    int s = 0;
    for (int b = g * 32; b < g * 32 + 32; ++b)
        s += bcnt[b * 16 + e];
    ps[e][g] = s;
    __syncthreads();

    if (tid < 16) {
        int run = 0;
        for (int gg = 0; gg < 16; ++gg) { gb[tid][gg] = run; run += ps[tid][gg]; }
        scnt[tid] = run;
        snch[tid] = (run + 127) >> 7;
    }
    __syncthreads();

    if (tid == 0) {
        int cc = 0, off = 0;
        for (int ee = 0; ee < 16; ++ee) {
            scum[ee] = cc; spoff[ee] = off;
            cc += snch[ee]; off += snch[ee] << 7;
        }
        scum[16] = cc;
        *total_chunks = cc;
    }
    __syncthreads();
    const int tot = scum[16];
    for (int idx = tid; idx < tot; idx += 256) {
        int ee = 0;
        #pragma unroll
        for (int k = 0; k < 15; ++k)
            if (idx >= scum[k + 1]) ee = k + 1;
        blk2e[idx] = ee;
        blk2chunk[idx] = idx - scum[ee];
    }
    if (tid < 16) poff[tid] = spoff[tid];

    {
        int run = spoff[e] + gb[e][g];
        for (int b = g * 32; b < g * 32 + 32; ++b) {
            bbase[b * 16 + e] = run;
            run += bcnt[b * 16 + e];
        }
    }

    for (int ee = 0; ee < 16; ++ee) {
        int start = spoff[ee] + scnt[ee];
        int end   = spoff[ee] + (snch[ee] << 7);
        for (int i = start + tid; i < end; i += 256)
            pair_tok[i] = -1;
    }
}

// ---------------- scatter pairs into expert bins ------------------------------
__global__ __launch_bounds__(256) void scatter_kernel(
    const int* __restrict__ top_idx, const int* __restrict__ rank,
    const int* __restrict__ bbase, int* __restrict__ pair_tok,
    int* __restrict__ slot_of)
{
    int i = blockIdx.x * 256 + threadIdx.x;   // 0..65535
    int t = i >> 1;
    int e = top_idx[i];
    int slot = bbase[(t >> 6) * 16 + e] + rank[i];
    pair_tok[slot] = t;
    slot_of[i] = slot;
}

// ---------------- grouped MFMA MLP: 1 block = (expert, 128 pairs) -------------
// LDS = 80 KB -> 2 blocks/CU. XOR-swizzled tiles (conflict-free ds_read_b128);
// W1/W2 staged via global_load_lds w16 with pre-swizzled source. Counted-vmcnt
// pipeline: W2(c) lands under layer1(c); W1(c+1) lands under layer2(c)+chunk top.
__device__ __forceinline__ void stage_w1(const unsigned short* w1e, short* W1s,
                                         int hcn, int wid, int lane) {
    #pragma unroll
    for (int k2 = 0; k2 < 2; ++k2) {
        int i2 = wid * 2 + k2;
        int r2 = i2 * 4 + (lane >> 4);          // hid-local row 0..63
        int s2 = lane & 15;                      // 16B slot 0..15
        gll16(w1e + (size_t)(hcn + r2) * 128 + ((s2 ^ (r2 & 15)) * 8),
              W1s + i2 * 512);
    }
}
__device__ __forceinline__ void stage_w2(const unsigned short* w2e, short* W2s,
                                         int hcn, int wid, int lane) {
    #pragma unroll
    for (int k2 = 0; k2 < 2; ++k2) {
        int i2 = wid * 2 + k2;
        int r2 = i2 * 8 + (lane >> 3);          // d row 0..127
        int s2 = lane & 7;                       // 16B slot 0..7
        gll16(w2e + (size_t)r2 * 512 + hcn + ((s2 ^ (r2 & 7)) * 8),
              W2s + i2 * 512);
    }
}

__global__ __launch_bounds__(512, 4) void moe_mfma_kernel(
    const unsigned short* __restrict__ xtb,
    const int* __restrict__ pair_tok, const int* __restrict__ blk2e,
    const int* __restrict__ blk2chunk, const int* __restrict__ poff,
    const int* __restrict__ total_chunks,
    const unsigned short* __restrict__ w1bt,   // [E][HID][D] bf16
    const float* __restrict__ b1,
    const unsigned short* __restrict__ w2bt,   // [E][D][HID] bf16
    const float* __restrict__ b2,
    unsigned short* __restrict__ pair_y)       // [Ppad][128] bf16
{
    __shared__ short Xs[128 * 128];    // [tok][d]   swz mask 15 (256B rows)
    __shared__ short Hs[128 * 64];     // [tok][hid] swz mask 7  (128B rows)
    __shared__ short W1s[64 * 128];    // [hid][d]   swz mask 15
    __shared__ short W2s[128 * 64];    // [d][hid]   swz mask 7

    // XCD-aware swizzle: 528 = 8*66; consecutive chunks (same expert) -> same
    // XCD so each XCD's ~2 experts' weights stay L2-resident (T1, m192).
    const int blk = (blockIdx.x & 7) * 66 + (blockIdx.x >> 3);
    if (blk >= *total_chunks) return;
    const int e  = blk2e[blk];
    const int p0 = poff[e] + (blk2chunk[blk] << 7);
    const int tid  = threadIdx.x;
    const int lane = tid & 63;
    const int wid  = tid >> 6;       // 0..7
    const int wm   = wid >> 1;       // 0..3 -> token rows wm*32
    const int wn   = wid & 1;        // 0..1
    const int l16  = lane & 15;
    const int lg   = lane >> 4;      // 0..3

    const unsigned short* w1e = w1bt + (size_t)e * 512 * 128;
    const unsigned short* w2e = w2bt + (size_t)e * 128 * 512;

    // prologue: issue chunk-0 stages (W1 first -> oldest in vmcnt FIFO)
    stage_w1(w1e, W1s, 0, wid, lane);
    stage_w2(w2e, W2s, 0, wid, lane);

    // stage X tile via registers (gather rows, zero-pad), swizzled stores
    #pragma unroll
    for (int i = 0; i < 4; ++i) {
        int lin = i * 512 + tid;              // 0..2047
        int row = lin >> 4, kc = lin & 15;
        int tok = pair_tok[p0 + row];
        short8v v = {};
        if (tok >= 0)
            v = *(const short8v*)(xtb + (size_t)tok * 128 + kc * 8);
        *(short8v*)(Xs + row * 128 + ((kc ^ (row & 15)) * 8)) = v;
    }

    f32x4 yacc[2][4];
    #pragma unroll
    for (int mi = 0; mi < 2; ++mi)
        #pragma unroll
        for (int ni = 0; ni < 4; ++ni)
            yacc[mi][ni] = (f32x4){0.f, 0.f, 0.f, 0.f};

    const int rowA0 = wm * 32 + l16, rowA1 = rowA0 + 16;

    for (int c = 0; c < 8; ++c) {
        // W1(c) = 2 oldest vmem ops of this wave; W2(c) may stay in flight.
        WAIT_VM2_LGKM0(); SBAR();

        // ---- layer 1: H_chunk[128 tok][64 hid] = relu(X @ W1 + b1) ----
        f32x4 hacc[2][2];
        #pragma unroll
        for (int mi = 0; mi < 2; ++mi)
            #pragma unroll
            for (int ni = 0; ni < 2; ++ni)
                hacc[mi][ni] = (f32x4){0.f, 0.f, 0.f, 0.f};

        #pragma unroll
        for (int kk = 0; kk < 4; ++kk) {
            int slot = kk * 4 + lg;
            short8v a0 = *(const short8v*)(Xs + rowA0 * 128 + ((slot ^ (rowA0 & 15)) * 8));
            short8v a1 = *(const short8v*)(Xs + rowA1 * 128 + ((slot ^ (rowA1 & 15)) * 8));
            #pragma unroll
            for (int ni = 0; ni < 2; ++ni) {
                int hr = wn * 32 + ni * 16 + l16;
                short8v bfr = *(const short8v*)(W1s + hr * 128 + ((slot ^ (hr & 15)) * 8));
                hacc[0][ni] = __builtin_amdgcn_mfma_f32_16x16x32_bf16(a0, bfr, hacc[0][ni], 0, 0, 0);
                hacc[1][ni] = __builtin_amdgcn_mfma_f32_16x16x32_bf16(a1, bfr, hacc[1][ni], 0, 0, 0);
            }
        }
        // relu + b1 -> Hs (swizzled b16 writes). D frag: col=lane&15, row=(lane>>4)*4+r
        #pragma unroll
        for (int ni = 0; ni < 2; ++ni) {
            int col = wn * 32 + ni * 16 + l16;
            float b1v = b1[e * 512 + (c << 6) + col];
            #pragma unroll
            for (int mi = 0; mi < 2; ++mi) {
                #pragma unroll
                for (int r = 0; r < 4; ++r) {
                    int m = wm * 32 + mi * 16 + lg * 4 + r;
                    float v = fmaxf(hacc[mi][ni][r] + b1v, 0.f);
                    Hs[m * 64 + (((col >> 3) ^ (m & 7)) << 3) + (col & 7)] = (short)f2bf(v);
                }
            }
        }
        // B: Hs visible to all; every wave's W1s ds_reads retired -> W1s free.
        WAIT_LGKM(); SBAR();

        // issue W1(c+1) into the freed buffer, then wait W2(c) (2 oldest).
        if (c < 7) { stage_w1(w1e, W1s, (c + 1) << 6, wid, lane); WAIT_VM2(); }
        else       { WAIT_VM0(); }
        SBAR();                                // all waves' W2(c) landed

        // ---- layer 2: Y += H_chunk @ W2[hc:hc+64, :] ----
        #pragma unroll
        for (int kk = 0; kk < 2; ++kk) {
            int slot = kk * 4 + lg;
            short8v a0 = *(const short8v*)(Hs + rowA0 * 64 + ((slot ^ (rowA0 & 7)) * 8));
            short8v a1 = *(const short8v*)(Hs + rowA1 * 64 + ((slot ^ (rowA1 & 7)) * 8));
            #pragma unroll
            for (int ni = 0; ni < 4; ++ni) {
                int dr = wn * 64 + ni * 16 + l16;
                short8v bfr = *(const short8v*)(W2s + dr * 64 + ((slot ^ (dr & 7)) * 8));
                yacc[0][ni] = __builtin_amdgcn_mfma_f32_16x16x32_bf16(a0, bfr, yacc[0][ni], 0, 0, 0);
                yacc[1][ni] = __builtin_amdgcn_mfma_f32_16x16x32_bf16(a1, bfr, yacc[1][ni], 0, 0, 0);
            }
        }
        // Drain layer-2 ds_reads BEFORE the barrier (R6 race-fix class).
        WAIT_LGKM(); SBAR();                   // W2s reads retired for all waves

        if (c < 7) stage_w2(w2e, W2s, (c + 1) << 6, wid, lane);
    }

    // epilogue: pair_y = bf16(Y + b2)
    #pragma unroll
    for (int ni = 0; ni < 4; ++ni) {
        int d = wn * 64 + ni * 16 + l16;
        float b2v = b2[e * 128 + d];
        #pragma unroll
        for (int mi = 0; mi < 2; ++mi) {
            #pragma unroll
            for (int r = 0; r < 4; ++r) {
                int m = wm * 32 + mi * 16 + lg * 4 + r;
                pair_y[(size_t)(p0 + m) * 128 + d] = f2bf(yacc[mi][ni][r] + b2v);
            }
        }
    }
}

// ---------------- combine: out[t] = p0*y0 + p1*y1 (NCHW store) ----------------
__global__ __launch_bounds__(256) void combine_kernel(
    const unsigned short* __restrict__ pair_y, const int* __restrict__ slot_of,
    const float* __restrict__ top_prob, float* __restrict__ out)
{
    __shared__ float ob[64][129];
    const int blk = blockIdx.x;               // 512
    const int b = blk >> 4;
    const int hw0 = (blk & 15) << 6;
    const int tid = threadIdx.x;
    #pragma unroll
    for (int i = 0; i < 4; ++i) {
        int lin = i * 256 + tid;              // 0..1023
        int tl = lin >> 4, dg = lin & 15;
        int t = b * 1024 + hw0 + tl;
        int s0 = slot_of[t * 2], s1 = slot_of[t * 2 + 1];
        float p0 = top_prob[t * 2], p1 = top_prob[t * 2 + 1];
        short8v y0 = *(const short8v*)(pair_y + (size_t)s0 * 128 + dg * 8);
        short8v y1 = *(const short8v*)(pair_y + (size_t)s1 * 128 + dg * 8);
        #pragma unroll
        for (int j = 0; j < 8; ++j)
            ob[tl][dg * 8 + j] = p0 * bf2f((unsigned short)y0[j]) + p1 * bf2f((unsigned short)y1[j]);
    }
    __syncthreads();
    #pragma unroll
    for (int i = 0; i < 32; ++i) {
        int lin = i * 256 + tid;
        int d = lin >> 6, hwl = lin & 63;
        out[((size_t)b * 128 + d) * 1024 + hw0 + hwl] = ob[hwl][d];
    }
}

// ---------------- fallback per-token expert kernel ----------------------------
__global__ __launch_bounds__(256) void moe_expert_kernel(
    const float* __restrict__ x,
    const int* __restrict__ top_idx, const float* __restrict__ top_prob,
    const float* __restrict__ w1, const float* __restrict__ b1,
    const float* __restrict__ w2, const float* __restrict__ b2,
    float* __restrict__ out)
{
    __shared__ float xsB[128];
    __shared__ float hb[512];

    const int tid = threadIdx.x;
    const int t = blockIdx.x;
    const int b = t >> 10, hw = t & 1023;

    if (tid < 128)
        xsB[tid] = x[((size_t)b * 128 + tid) * NHW + hw];
    __syncthreads();

    float oacc = 0.f;
    #pragma unroll
    for (int k = 0; k < 2; ++k) {
        const int e = top_idx[t * 2 + k];
        const float pw = top_prob[t * 2 + k];
        const float* W1 = w1 + (size_t)e * (128 * 512);
        float a0 = 0.f, a1 = 0.f;
        for (int d = 0; d < 128; ++d) {
            float xv = xsB[d];
            a0 = fmaf(xv, W1[d * 512 + tid], a0);
            a1 = fmaf(xv, W1[d * 512 + tid + 256], a1);
        }
        hb[tid]       = fmaxf(a0 + b1[e * 512 + tid], 0.f);
        hb[tid + 256] = fmaxf(a1 + b1[e * 512 + tid + 256], 0.f);
        __syncthreads();
        if (tid < 128) {
            const float* W2 = w2 + (size_t)e * (512 * 128);
            float a = 0.f;
            for (int h = 0; h < 512; ++h)
                a = fmaf(hb[h], W2[h * 128 + tid], a);
            oacc = fmaf(pw, a + b2[e * 128 + tid], oacc);
        }
        __syncthreads();
    }
    if (tid < 128)
        out[((size_t)b * 128 + tid) * NHW + hw] = oacc;
}

// ---------------- host launch -------------------------------------------------
extern "C" void kernel_launch(void* const* d_in, const int* in_sizes, int n_in,
                              void* d_out, int out_size, void* d_ws, size_t ws_size,
                              hipStream_t stream) {
    const float* x       = (const float*)d_in[0];
    const float* gate_w  = (const float*)d_in[1];
    const float* gate_b  = (const float*)d_in[2];
    const float* noise_w = (const float*)d_in[3];
    const float* noise_b = (const float*)d_in[4];
    const float* w1      = (const float*)d_in[5];
    const float* b1      = (const float*)d_in[6];
    const float* w2      = (const float*)d_in[7];
    const float* b2      = (const float*)d_in[8];

    float* out   = (float*)d_out;                   // [32,128,32,32]
    float* gates = out + (size_t)NB * NC * NHW;     // [T,16]

    // workspace layout (byte offsets)
    const size_t OFF_POFF   = 0;          // 16 ints
    const size_t OFF_TOTAL  = 1024;       // 1 int
    const size_t OFF_B2E    = 4096;       // 544 ints
    const size_t OFF_B2C    = 8192;       // 544 ints
    const size_t OFF_TIDX   = 12288;      // T*2 ints
    const size_t OFF_RANK   = OFF_TIDX  + (size_t)NT * 2 * 4;
    const size_t OFF_SLOT   = OFF_RANK  + (size_t)NT * 2 * 4;
    const size_t OFF_PROB   = OFF_SLOT  + (size_t)NT * 2 * 4;
    const size_t OFF_BCNT   = OFF_PROB  + (size_t)NT * 2 * 4;     // 512*16 ints
    const size_t OFF_BBASE  = OFF_BCNT  + (size_t)NGBLK * 16 * 4;
    const size_t OFF_XTB    = OFF_BBASE + (size_t)NGBLK * 16 * 4;
    const size_t OFF_W1BT   = OFF_XTB   + (size_t)NT * 128 * 2;
    const size_t OFF_W2BT   = OFF_W1BT  + (size_t)NE * 512 * 128 * 2;
    const size_t OFF_PTOK   = OFF_W2BT  + (size_t)NE * 128 * 512 * 2;
    const size_t NPAIR_PAD  = 67584;
    const size_t OFF_PAIRY  = OFF_PTOK  + NPAIR_PAD * 4;
    const size_t NEED       = OFF_PAIRY + NPAIR_PAD * 128 * 2;   // pair_y bf16

    char* ws = (char*)d_ws;
    int*   poff     = (int*)(ws + OFF_POFF);
    int*   total_ch = (int*)(ws + OFF_TOTAL);
    int*   blk2e    = (int*)(ws + OFF_B2E);
    int*   blk2c    = (int*)(ws + OFF_B2C);
    int*   top_idx  = (int*)(ws + OFF_TIDX);
    int*   rank     = (int*)(ws + OFF_RANK);
    int*   slot_of  = (int*)(ws + OFF_SLOT);
    float* top_prob = (float*)(ws + OFF_PROB);
    int*   bcnt     = (int*)(ws + OFF_BCNT);
    int*   bbase    = (int*)(ws + OFF_BBASE);
    unsigned short* xtb    = (unsigned short*)(ws + OFF_XTB);
    unsigned short* w1bt   = (unsigned short*)(ws + OFF_W1BT);
    unsigned short* w2bt   = (unsigned short*)(ws + OFF_W2BT);
    int*   pair_tok = (int*)(ws + OFF_PTOK);
    unsigned short* pair_y = (unsigned short*)(ws + OFF_PAIRY);

    const int use_new = (ws_size >= NEED) ? 1 : 0;

    // gate (blocks 0..511) + weight transpose (blocks 512..1023) in one launch
    moe_gate_tw_kernel<<<use_new ? (NGBLK + 512) : NGBLK, 256, 0, stream>>>(
        x, gate_w, gate_b, noise_w, noise_b,
        gates, top_idx, top_prob, rank, bcnt, xtb,
        w1, w1bt, w2, w2bt, use_new);

    if (use_new) {
        scan_kernel<<<1, 256, 0, stream>>>(bcnt, poff, blk2e, blk2c, total_ch,
                                           bbase, pair_tok);
        scatter_kernel<<<NT * 2 / 256, 256, 0, stream>>>(top_idx, rank, bbase,
                                                         pair_tok, slot_of);
        moe_mfma_kernel<<<528, 512, 0, stream>>>(
            xtb, pair_tok, blk2e, blk2c, poff, total_ch,
            w1bt, b1, w2bt, b2, pair_y);
        combine_kernel<<<512, 256, 0, stream>>>(pair_y, slot_of, top_prob, out);
    } else {
        moe_expert_kernel<<<NT, 256, 0, stream>>>(
            x, top_idx, top_prob, w1, b1, w2, b2, out);
    }
}